// Round 1
// baseline (188.320 us; speedup 1.0000x reference)
//
#include <hip/hip_runtime.h>
#include <hip/hip_bf16.h>

// GroupAttention: channel-axis attention (Swin-V2 style) fully fused, fp32.
// B=256, N=80 (tokens axis = feature dim here), C=256 channels, H=8 heads, hd=10.

#define B_SZ   256
#define N_TOK  80
#define C_CH   256
#define H_HEADS 8
#define HD     10
#define RPE_H  512
#define TBL_R  765   // (2*128-1)*(2*2-1)
#define EPS_   5e-5f

// ---------------- Kernel 1: CPB MLP -> bias_table16[765][8] = 16*sigmoid(mlp) ----
__global__ __launch_bounds__(64) void cpb_kernel(const float* __restrict__ table,
                                                 const float* __restrict__ w1,
                                                 const float* __restrict__ b1,
                                                 const float* __restrict__ w2,
                                                 float* __restrict__ bt)
{
    int r = blockIdx.x;      // 0..764
    int l = threadIdx.x;     // 0..63
    float t0 = table[r * 2 + 0];
    float t1 = table[r * 2 + 1];
    float part[8];
#pragma unroll
    for (int h = 0; h < 8; ++h) part[h] = 0.f;
    for (int j = l; j < RPE_H; j += 64) {
        float hv = fmaf(t0, w1[j * 2 + 0], fmaf(t1, w1[j * 2 + 1], b1[j]));
        hv = fmaxf(hv, 0.f);
#pragma unroll
        for (int h = 0; h < 8; ++h)
            part[h] = fmaf(hv, w2[h * RPE_H + j], part[h]);
    }
#pragma unroll
    for (int h = 0; h < 8; ++h) {
#pragma unroll
        for (int off = 32; off > 0; off >>= 1)
            part[h] += __shfl_xor(part[h], off, 64);
    }
    if (l == 0) {
#pragma unroll
        for (int h = 0; h < 8; ++h)
            bt[r * 8 + h] = 16.f / (1.f + __expf(-part[h]));
    }
}

// ---------------- Kernel 2: expand rpb_t[h][e][c] = bt[rel_index[c][e]][h] --------
__global__ __launch_bounds__(256) void expand_kernel(const float* __restrict__ bt,
                                                     const int* __restrict__ rel_index,
                                                     float* __restrict__ rpb_t)
{
    int idx = blockIdx.x * 256 + threadIdx.x;   // < 8*256*256
    int c = idx & 255;
    int e = (idx >> 8) & 255;
    int h = idx >> 16;
    rpb_t[idx] = bt[rel_index[c * 256 + e] * 8 + h];
}

// ---------------- Kernel 3: fused qkv-proj + cosine attn + softmax + PV ----------
// grid = B*H blocks, 256 threads (one per channel c). out2 layout: [B][80][C].
__global__ __launch_bounds__(256, 4) void attn_kernel(const float* __restrict__ x,
                                                      const float* __restrict__ w_qkv,
                                                      const float* __restrict__ q_bias,
                                                      const float* __restrict__ v_bias,
                                                      const float* __restrict__ rpb_t,
                                                      float* __restrict__ out2)
{
    __shared__ float w_lds[N_TOK * 32];     // w^T[n][j], j in [0,30), padded to 32
    __shared__ float k_lds[C_CH * 12];      // [e][d], padded to 12 for b128 align
    __shared__ float v_lds[C_CH * 12];

    const int bid = blockIdx.x;
    const int b = bid >> 3;
    const int h = bid & 7;
    const int tid = threadIdx.x;
    const int c = tid;

    // stage the head's 30 rows of w_qkv, transposed: w_lds[n*32 + j], j = s*10+d
    for (int i = tid; i < 30 * N_TOK; i += 256) {
        int j = i / N_TOK, n = i - j * N_TOK;
        int s = j / 10, d = j - s * 10;
        w_lds[n * 32 + j] = w_qkv[(s * N_TOK + h * 10 + d) * N_TOK + n];
    }
    __syncthreads();

    // qkv projection for channel c: acc[0..9]=q, [10..19]=k, [20..29]=v
    float acc[30];
#pragma unroll
    for (int d = 0; d < 10; ++d) {
        acc[d]      = q_bias[h * 10 + d];
        acc[10 + d] = 0.f;
        acc[20 + d] = v_bias[h * 10 + d];
    }
    const float* xb = x + (size_t)b * N_TOK * C_CH + c;
    for (int n = 0; n < N_TOK; ++n) {
        float xv = xb[n * C_CH];
        const float4* wr = reinterpret_cast<const float4*>(&w_lds[n * 32]);
        float4 wv4[8];
#pragma unroll
        for (int q4 = 0; q4 < 8; ++q4) wv4[q4] = wr[q4];
        const float* wv = reinterpret_cast<const float*>(wv4);
#pragma unroll
        for (int j = 0; j < 30; ++j)
            acc[j] = fmaf(xv, wv[j], acc[j]);
    }

    // cosine-normalize q, k (lane-local)
    float qss = 0.f, kss = 0.f;
#pragma unroll
    for (int d = 0; d < 10; ++d) {
        qss = fmaf(acc[d], acc[d], qss);
        kss = fmaf(acc[10 + d], acc[10 + d], kss);
    }
    float qs = 1.f / (sqrtf(qss) + EPS_);
    float ks = 1.f / (sqrtf(kss) + EPS_);
    float qreg[10];
#pragma unroll
    for (int d = 0; d < 10; ++d) qreg[d] = acc[d] * qs;
#pragma unroll
    for (int d = 0; d < 10; ++d) {
        k_lds[c * 12 + d] = acc[10 + d] * ks;
        v_lds[c * 12 + d] = acc[20 + d];
    }
    __syncthreads();

    // flash-style (max-free: logits <= 17, exp safe in fp32) softmax + PV
    float s = 0.f;
    float o[10];
#pragma unroll
    for (int d = 0; d < 10; ++d) o[d] = 0.f;
    const float* rp = rpb_t + (size_t)h * C_CH * C_CH + c;

#pragma unroll 2
    for (int e = 0; e < C_CH; ++e) {
        const float4* kp = reinterpret_cast<const float4*>(&k_lds[e * 12]);
        float4 k0 = kp[0], k1 = kp[1];
        float2 k2 = *reinterpret_cast<const float2*>(&k_lds[e * 12 + 8]);
        float logit = qreg[0] * k0.x;
        logit = fmaf(qreg[1], k0.y, logit);
        logit = fmaf(qreg[2], k0.z, logit);
        logit = fmaf(qreg[3], k0.w, logit);
        logit = fmaf(qreg[4], k1.x, logit);
        logit = fmaf(qreg[5], k1.y, logit);
        logit = fmaf(qreg[6], k1.z, logit);
        logit = fmaf(qreg[7], k1.w, logit);
        logit = fmaf(qreg[8], k2.x, logit);
        logit = fmaf(qreg[9], k2.y, logit);
        logit += rp[e * C_CH];
        float p = __expf(logit);
        s += p;
        const float4* vp = reinterpret_cast<const float4*>(&v_lds[e * 12]);
        float4 v0 = vp[0], v1 = vp[1];
        float2 v2 = *reinterpret_cast<const float2*>(&v_lds[e * 12 + 8]);
        o[0] = fmaf(p, v0.x, o[0]);
        o[1] = fmaf(p, v0.y, o[1]);
        o[2] = fmaf(p, v0.z, o[2]);
        o[3] = fmaf(p, v0.w, o[3]);
        o[4] = fmaf(p, v1.x, o[4]);
        o[5] = fmaf(p, v1.y, o[5]);
        o[6] = fmaf(p, v1.z, o[6]);
        o[7] = fmaf(p, v1.w, o[7]);
        o[8] = fmaf(p, v2.x, o[8]);
        o[9] = fmaf(p, v2.y, o[9]);
    }
    float inv = 1.f / s;
    float* op = out2 + ((size_t)b * N_TOK + h * 10) * C_CH + c;
#pragma unroll
    for (int d = 0; d < 10; ++d)
        op[d * C_CH] = o[d] * inv;
}

// ---------------- Kernel 4: output projection (in-place safe per-block) ----------
// out[b][no][c] = sum_n out2[b][n][c] * proj_w[no][n] + proj_b[no]
__global__ __launch_bounds__(256) void proj_kernel(const float* __restrict__ out2,
                                                   const float* __restrict__ proj_w,
                                                   const float* __restrict__ proj_b,
                                                   float* __restrict__ out)
{
    __shared__ float in_lds[N_TOK * C_CH];   // 80 KB
    __shared__ float w_lds[N_TOK * N_TOK];   // w^T[n][no], 25.6 KB
    const int b = blockIdx.x;
    const int tid = threadIdx.x;
    const float* src = out2 + (size_t)b * N_TOK * C_CH;
    for (int i = tid; i < N_TOK * C_CH; i += 256) in_lds[i] = src[i];
    for (int i = tid; i < N_TOK * N_TOK; i += 256) {
        int no = i / N_TOK, n = i - no * N_TOK;
        w_lds[n * N_TOK + no] = proj_w[i];
    }
    __syncthreads();
    const int c = tid;
    float* dst = out + (size_t)b * N_TOK * C_CH + c;
#pragma unroll 1
    for (int ob = 0; ob < 5; ++ob) {
        float accp[16];
#pragma unroll
        for (int j = 0; j < 16; ++j) accp[j] = proj_b[ob * 16 + j];
        for (int n = 0; n < N_TOK; ++n) {
            float iv = in_lds[n * C_CH + c];
            const float4* wp = reinterpret_cast<const float4*>(&w_lds[n * N_TOK + ob * 16]);
            float4 w0 = wp[0], w1 = wp[1], w2 = wp[2], w3 = wp[3];
            accp[0]  = fmaf(iv, w0.x, accp[0]);
            accp[1]  = fmaf(iv, w0.y, accp[1]);
            accp[2]  = fmaf(iv, w0.z, accp[2]);
            accp[3]  = fmaf(iv, w0.w, accp[3]);
            accp[4]  = fmaf(iv, w1.x, accp[4]);
            accp[5]  = fmaf(iv, w1.y, accp[5]);
            accp[6]  = fmaf(iv, w1.z, accp[6]);
            accp[7]  = fmaf(iv, w1.w, accp[7]);
            accp[8]  = fmaf(iv, w2.x, accp[8]);
            accp[9]  = fmaf(iv, w2.y, accp[9]);
            accp[10] = fmaf(iv, w2.z, accp[10]);
            accp[11] = fmaf(iv, w2.w, accp[11]);
            accp[12] = fmaf(iv, w3.x, accp[12]);
            accp[13] = fmaf(iv, w3.y, accp[13]);
            accp[14] = fmaf(iv, w3.z, accp[14]);
            accp[15] = fmaf(iv, w3.w, accp[15]);
        }
#pragma unroll
        for (int j = 0; j < 16; ++j)
            dst[(ob * 16 + j) * C_CH] = accp[j];
    }
}

extern "C" void kernel_launch(void* const* d_in, const int* in_sizes, int n_in,
                              void* d_out, int out_size, void* d_ws, size_t ws_size,
                              hipStream_t stream) {
    const float* x        = (const float*)d_in[0];
    const float* w_qkv    = (const float*)d_in[1];
    const float* q_bias   = (const float*)d_in[2];
    const float* v_bias   = (const float*)d_in[3];
    const float* w1       = (const float*)d_in[4];
    const float* b1       = (const float*)d_in[5];
    const float* w2       = (const float*)d_in[6];
    const float* proj_w   = (const float*)d_in[7];
    const float* proj_b   = (const float*)d_in[8];
    const float* table    = (const float*)d_in[9];
    const int*   rel_idx  = (const int*)d_in[10];
    float* out = (float*)d_out;

    float* bt    = (float*)d_ws;                         // 765*8 floats
    float* rpb_t = (float*)((char*)d_ws + 32768);        // 8*256*256 floats = 2 MB

    cpb_kernel<<<TBL_R, 64, 0, stream>>>(table, w1, b1, w2, bt);
    expand_kernel<<<(H_HEADS * C_CH * C_CH) / 256, 256, 0, stream>>>(bt, rel_idx, rpb_t);
    // attention writes out2 into d_out (layout [B][80][C]); proj then runs in-place:
    // each proj block fully reads its b-slice into LDS before overwriting it.
    attn_kernel<<<B_SZ * H_HEADS, 256, 0, stream>>>(x, w_qkv, q_bias, v_bias, rpb_t, out);
    proj_kernel<<<B_SZ, 256, 0, stream>>>(out, proj_w, proj_b, out);
}

// Round 2
// 148.634 us; speedup vs baseline: 1.2670x; 1.2670x over previous
//
#include <hip/hip_runtime.h>
#include <hip/hip_bf16.h>

// GroupAttention: channel-axis attention, bf16-MFMA core, fp32 softmax/proj.
// B=256, N=80, C=256, H=8, hd=10.

#define B_SZ    256
#define N_TOK   80
#define C_CH    256
#define H_HEADS 8
#define RPE_H   512
#define TBL_R   765   // (2*128-1)*(2*2-1)
#define EPS_    5e-5f
#define L2E     1.44269504088896f

typedef __bf16 bf16x8 __attribute__((ext_vector_type(8)));
typedef float  f32x4  __attribute__((ext_vector_type(4)));

// ---------------- Kernel 1: CPB MLP -> btT[h][765] = 16*sigmoid(mlp)*log2(e) ----
__global__ __launch_bounds__(64) void cpb_kernel(const float* __restrict__ table,
                                                 const float* __restrict__ w1,
                                                 const float* __restrict__ b1,
                                                 const float* __restrict__ w2,
                                                 float* __restrict__ btT)
{
    int r = blockIdx.x;      // 0..764
    int l = threadIdx.x;     // 0..63
    float t0 = table[r * 2 + 0];
    float t1 = table[r * 2 + 1];
    float part[8];
#pragma unroll
    for (int h = 0; h < 8; ++h) part[h] = 0.f;
    for (int j = l; j < RPE_H; j += 64) {
        float hv = fmaf(t0, w1[j * 2 + 0], fmaf(t1, w1[j * 2 + 1], b1[j]));
        hv = fmaxf(hv, 0.f);
#pragma unroll
        for (int h = 0; h < 8; ++h)
            part[h] = fmaf(hv, w2[h * RPE_H + j], part[h]);
    }
#pragma unroll
    for (int h = 0; h < 8; ++h) {
#pragma unroll
        for (int off = 32; off > 0; off >>= 1)
            part[h] += __shfl_xor(part[h], off, 64);
    }
    if (l == 0) {
#pragma unroll
        for (int h = 0; h < 8; ++h)
            btT[h * TBL_R + r] = L2E * 16.f / (1.f + __expf(-part[h]));
    }
}

// ---------------- Kernel 2: fused qkv-proj (fp32) + MFMA attention ---------------
// grid = B*H blocks, 256 threads (4 waves). out2 layout: [B][80][C] (into d_out).
__global__ __launch_bounds__(256, 3) void attn_kernel(const float* __restrict__ x,
                                                      const float* __restrict__ w_qkv,
                                                      const float* __restrict__ q_bias,
                                                      const float* __restrict__ v_bias,
                                                      const float* __restrict__ btT,
                                                      float* __restrict__ out2)
{
    __shared__ __hip_bfloat16 Qs[C_CH * 16];        // [c][16], k 10..15 zero
    __shared__ __hip_bfloat16 Ks[C_CH * 16];        // [e][16]
    __shared__ __hip_bfloat16 Vts[16 * 264];        // [d][e], padded stride 264
    __shared__ float bt_lds[TBL_R];                 // head's bias column, *log2(e)
    __shared__ __align__(16) char ubuf[C_CH * 32 * 2];  // phase1: w_lds / phase2: Ps
    float* w_lds = (float*)ubuf;                    // [80][32]
    __hip_bfloat16* Ps = (__hip_bfloat16*)ubuf;     // [256][32]

    const int tid = threadIdx.x;
    const int b = blockIdx.x >> 3;
    const int h = blockIdx.x & 7;

    // ---- stage per-head qkv weights (transposed) + bias table column ----
    for (int i = tid; i < 30 * N_TOK; i += 256) {
        int j = i / N_TOK, n = i - j * N_TOK;
        int s = j / 10, d = j - s * 10;
        w_lds[n * 32 + j] = w_qkv[(s * N_TOK + h * 10 + d) * N_TOK + n];
    }
    for (int i = tid; i < TBL_R; i += 256) bt_lds[i] = btT[h * TBL_R + i];
    __syncthreads();

    // ---- phase 1: qkv projection for channel c = tid (fp32) ----
    float acc[30];
#pragma unroll
    for (int d = 0; d < 10; ++d) {
        acc[d]      = q_bias[h * 10 + d];
        acc[10 + d] = 0.f;
        acc[20 + d] = v_bias[h * 10 + d];
    }
    {
        const float* xb = x + (size_t)b * N_TOK * C_CH + tid;
        for (int n = 0; n < N_TOK; ++n) {
            float xv = xb[n * C_CH];
            const float4* wr = reinterpret_cast<const float4*>(&w_lds[n * 32]);
            float4 wv4[8];
#pragma unroll
            for (int q4 = 0; q4 < 8; ++q4) wv4[q4] = wr[q4];
            const float* wv = reinterpret_cast<const float*>(wv4);
#pragma unroll
            for (int j = 0; j < 30; ++j)
                acc[j] = fmaf(xv, wv[j], acc[j]);
        }
    }
    float qss = 0.f, kss = 0.f;
#pragma unroll
    for (int d = 0; d < 10; ++d) {
        qss = fmaf(acc[d], acc[d], qss);
        kss = fmaf(acc[10 + d], acc[10 + d], kss);
    }
    float qs = 1.f / (sqrtf(qss) + EPS_);
    float ks = 1.f / (sqrtf(kss) + EPS_);
    {
        const int c = tid;
#pragma unroll
        for (int d = 0; d < 10; ++d) {
            Qs[c * 16 + d]  = __float2bfloat16(acc[d] * qs);
            Ks[c * 16 + d]  = __float2bfloat16(acc[10 + d] * ks);
            Vts[d * 264 + c] = __float2bfloat16(acc[20 + d]);
        }
#pragma unroll
        for (int d = 10; d < 16; ++d) {
            Qs[c * 16 + d]  = __float2bfloat16(0.f);
            Ks[c * 16 + d]  = __float2bfloat16(0.f);
            Vts[d * 264 + c] = __float2bfloat16(0.f);
        }
    }
    __syncthreads();

    // ---- phase 2: MFMA attention; each wave owns 64 query rows; no barriers ----
    const int lane = tid & 63, wv = tid >> 6;
    const int g = lane >> 4, m = lane & 15;

    bf16x8 zf;
#pragma unroll
    for (int i = 0; i < 8; ++i) zf[i] = (__bf16)0.0f;
    f32x4 zacc = {0.f, 0.f, 0.f, 0.f};

    // Q fragments for this wave's 4 row-tiles (k = 8*g + j assumed; lanes>=32 zero)
    bf16x8 qf[4];
#pragma unroll
    for (int t = 0; t < 4; ++t) {
        bf16x8 f = zf;
        if (lane < 32) f = *reinterpret_cast<const bf16x8*>(&Qs[(wv * 64 + t * 16 + m) * 16 + g * 8]);
        qf[t] = f;
    }
    // bias-index precompute: idx = cterm - eterm, cterm includes +382
    int cterm[4][4];
#pragma unroll
    for (int t = 0; t < 4; ++t)
#pragma unroll
        for (int r = 0; r < 4; ++r) {
            int cc = wv * 64 + t * 16 + 4 * g + r;
            cterm[t][r] = 3 * (cc >> 1) + (cc & 1) + 382;
        }
    const int eterm_m = 3 * (m >> 1) + (m & 1);

    f32x4 Oacc[4];
#pragma unroll
    for (int t = 0; t < 4; ++t) Oacc[t] = zacc;
    float s_part[4][4];
#pragma unroll
    for (int t = 0; t < 4; ++t)
#pragma unroll
        for (int r = 0; r < 4; ++r) s_part[t][r] = 0.f;

    for (int e0 = 0; e0 < C_CH; e0 += 32) {
        // K fragments (2 e-tiles)
        bf16x8 kf[2];
#pragma unroll
        for (int et = 0; et < 2; ++et) {
            bf16x8 f = zf;
            if (lane < 32) f = *reinterpret_cast<const bf16x8*>(&Ks[(e0 + et * 16 + m) * 16 + g * 8]);
            kf[et] = f;
        }
        // QK^T: 8 tiles (C/D: col=e=m, row=c=4g+r)
        f32x4 sacc[4][2];
#pragma unroll
        for (int t = 0; t < 4; ++t)
#pragma unroll
            for (int et = 0; et < 2; ++et)
                sacc[t][et] = __builtin_amdgcn_mfma_f32_16x16x32_bf16(qf[t], kf[et], zacc, 0, 0, 0);
        // softmax numerator (max-free: logit<=1, bias<=16) + P store (wave-private)
#pragma unroll
        for (int et = 0; et < 2; ++et) {
            int eterm = 3 * ((e0 + et * 16) >> 1) + eterm_m;
#pragma unroll
            for (int t = 0; t < 4; ++t)
#pragma unroll
                for (int r = 0; r < 4; ++r) {
                    float bias2 = bt_lds[cterm[t][r] - eterm];
                    float p = exp2f(fmaf(sacc[t][et][r], L2E, bias2));
                    s_part[t][r] += p;
                    Ps[(wv * 64 + t * 16 + 4 * g + r) * 32 + et * 16 + m] = __float2bfloat16(p);
                }
        }
        // PV: K-step = this 32-e chunk
        bf16x8 vf = *reinterpret_cast<const bf16x8*>(&Vts[m * 264 + e0 + g * 8]);
#pragma unroll
        for (int t = 0; t < 4; ++t) {
            bf16x8 pf = *reinterpret_cast<const bf16x8*>(&Ps[(wv * 64 + t * 16 + m) * 32 + g * 8]);
            Oacc[t] = __builtin_amdgcn_mfma_f32_16x16x32_bf16(pf, vf, Oacc[t], 0, 0, 0);
        }
    }

    // row sums: reduce over the 16 lanes of each row-group (same g, varying m)
    float rinv[4][4];
#pragma unroll
    for (int t = 0; t < 4; ++t)
#pragma unroll
        for (int r = 0; r < 4; ++r) {
            float s = s_part[t][r];
            s += __shfl_xor(s, 1);
            s += __shfl_xor(s, 2);
            s += __shfl_xor(s, 4);
            s += __shfl_xor(s, 8);
            rinv[t][r] = 1.f / s;
        }
    // write: O[c][d] -> out2[b][h*10+d][c]; lane col = d = m
    if (m < 10) {
        float* op = out2 + (size_t)b * N_TOK * C_CH + (h * 10 + m) * C_CH;
#pragma unroll
        for (int t = 0; t < 4; ++t)
#pragma unroll
            for (int r = 0; r < 4; ++r)
                op[wv * 64 + t * 16 + 4 * g + r] = Oacc[t][r] * rinv[t][r];
    }
}

// ---------------- Kernel 3: output projection, c-split, in-place safe ------------
// block = (b, cq): c in [cq*64, cq*64+64). out[b][no][c] = sum_n in[b][n][c]*W[no][n]+b
__global__ __launch_bounds__(256, 3) void proj_kernel(const float* __restrict__ out2,
                                                      const float* __restrict__ proj_w,
                                                      const float* __restrict__ proj_b,
                                                      float* __restrict__ out)
{
    __shared__ float in_lds[N_TOK * 64];     // 20 KB
    __shared__ float w_lds[N_TOK * N_TOK];   // w^T[n][no], 25.6 KB
    const int cq = blockIdx.x & 3;
    const int b  = blockIdx.x >> 2;
    const int tid = threadIdx.x;
    const float* src = out2 + (size_t)b * N_TOK * C_CH + cq * 64;
    for (int i = tid; i < N_TOK * 64; i += 256) {
        int n = i >> 6, cl = i & 63;
        in_lds[i] = src[n * C_CH + cl];
    }
    for (int i = tid; i < N_TOK * N_TOK; i += 256) {
        int no = i / N_TOK, n = i - no * N_TOK;
        w_lds[n * N_TOK + no] = proj_w[i];
    }
    __syncthreads();
    const int cl = tid & 63, ng = tid >> 6;    // wave-uniform ng -> 20 outputs
    float accp[20];
#pragma unroll
    for (int j = 0; j < 20; ++j) accp[j] = proj_b[ng * 20 + j];
    for (int n = 0; n < N_TOK; ++n) {
        float iv = in_lds[n * 64 + cl];
        const float4* wr4 = reinterpret_cast<const float4*>(&w_lds[n * N_TOK + ng * 20]);
        float4 wq[5];
#pragma unroll
        for (int q4 = 0; q4 < 5; ++q4) wq[q4] = wr4[q4];
        const float* wv = reinterpret_cast<const float*>(wq);
#pragma unroll
        for (int j = 0; j < 20; ++j)
            accp[j] = fmaf(iv, wv[j], accp[j]);
    }
    float* dst = out + (size_t)b * N_TOK * C_CH + cq * 64 + cl;
#pragma unroll
    for (int j = 0; j < 20; ++j)
        dst[(ng * 20 + j) * C_CH] = accp[j];
}

extern "C" void kernel_launch(void* const* d_in, const int* in_sizes, int n_in,
                              void* d_out, int out_size, void* d_ws, size_t ws_size,
                              hipStream_t stream) {
    const float* x        = (const float*)d_in[0];
    const float* w_qkv    = (const float*)d_in[1];
    const float* q_bias   = (const float*)d_in[2];
    const float* v_bias   = (const float*)d_in[3];
    const float* w1       = (const float*)d_in[4];
    const float* b1       = (const float*)d_in[5];
    const float* w2       = (const float*)d_in[6];
    const float* proj_w   = (const float*)d_in[7];
    const float* proj_b   = (const float*)d_in[8];
    const float* table    = (const float*)d_in[9];
    float* out = (float*)d_out;

    float* btT = (float*)d_ws;   // [8][765] fp32, 24.5 KB

    cpb_kernel<<<TBL_R, 64, 0, stream>>>(table, w1, b1, w2, btT);
    // attention writes out2 ([B][80][C]) into d_out; proj then runs in-place:
    // each proj block fully reads its (b, c-slice) into LDS before overwriting it.
    attn_kernel<<<B_SZ * H_HEADS, 256, 0, stream>>>(x, w_qkv, q_bias, v_bias, btT, out);
    proj_kernel<<<B_SZ * 4, 256, 0, stream>>>(out, proj_w, proj_b, out);
}

// Round 3
// 133.345 us; speedup vs baseline: 1.4123x; 1.1147x over previous
//
#include <hip/hip_runtime.h>
#include <hip/hip_bf16.h>

// GroupAttention fully-MFMA: per-b mega-kernel (qkv GEMM + attention) + MFMA proj.
// B=256, N=80, C=256, H=8, hd=10 (padded to 16 in the qkv GEMM).

#define B_SZ   256
#define N_TOK  80
#define C_CH   256
#define RPE_H  512
#define TBL_R  765
#define EPS_   5e-5f
#define L2E    1.44269504088896f

typedef __bf16 bf16x8 __attribute__((ext_vector_type(8)));
typedef float  f32x4  __attribute__((ext_vector_type(4)));
typedef unsigned long long ull;

// LDS byte offsets (mega kernel), total 158,208 <= 163,840
#define XS_OFF 0        // Xs[256][104] bf16, row stride 208 B
#define QH_OFF 53248    // Qh[2][256][16] bf16, row stride 32 B
#define KH_OFF 69632    // Kh[2][256][24] bf16, row stride 48 B
#define VT_OFF 94208    // Vt[2][16][264] bf16, row stride 528 B
#define PS_OFF 111104   // Ps[8][64][40] bf16, wave base +5120, row stride 80 B
#define BT_OFF 152064   // btl[2][768] f32
#define SMEM_TOT 158208

__device__ inline unsigned short bfb(float f) {
    __hip_bfloat16 h = __float2bfloat16(f);
    return reinterpret_cast<unsigned short&>(h);
}
__device__ inline float bf2f(unsigned short u) {
    unsigned int w = ((unsigned int)u) << 16;
    return __uint_as_float(w);
}

// ---------------- Kernel 1: CPB MLP -> btT[h][765] = 16*sigmoid(mlp)*log2(e) ----
__global__ __launch_bounds__(64) void cpb_kernel(const float* __restrict__ table,
                                                 const float* __restrict__ w1,
                                                 const float* __restrict__ b1,
                                                 const float* __restrict__ w2,
                                                 float* __restrict__ btT)
{
    int r = blockIdx.x;
    int l = threadIdx.x;
    float t0 = table[r * 2 + 0];
    float t1 = table[r * 2 + 1];
    float part[8];
#pragma unroll
    for (int h = 0; h < 8; ++h) part[h] = 0.f;
    for (int j = l; j < RPE_H; j += 64) {
        float hv = fmaf(t0, w1[j * 2 + 0], fmaf(t1, w1[j * 2 + 1], b1[j]));
        hv = fmaxf(hv, 0.f);
#pragma unroll
        for (int h = 0; h < 8; ++h)
            part[h] = fmaf(hv, w2[h * RPE_H + j], part[h]);
    }
#pragma unroll
    for (int h = 0; h < 8; ++h) {
#pragma unroll
        for (int off = 32; off > 0; off >>= 1)
            part[h] += __shfl_xor(part[h], off, 64);
    }
    if (l == 0) {
#pragma unroll
        for (int h = 0; h < 8; ++h)
            btT[h * TBL_R + r] = L2E * 16.f / (1.f + __expf(-part[h]));
    }
}

// ---------------- Kernel 2: mega (per b): qkv MFMA GEMM + attention ----------
// out2 = d_out viewed as u32 words [b][80][256]: (bf16 hi | bf16 lo<<16).
__global__ __launch_bounds__(512, 2) void mega_kernel(const float* __restrict__ x,
                                                      const float* __restrict__ w_qkv,
                                                      const float* __restrict__ q_bias,
                                                      const float* __restrict__ v_bias,
                                                      const float* __restrict__ btT,
                                                      unsigned int* __restrict__ out2)
{
    __shared__ __align__(16) char smem[SMEM_TOT];
    const int tid = threadIdx.x;
    const int b = blockIdx.x;
    const int lane = tid & 63, w = tid >> 6;
    const int g = lane >> 4, m = lane & 15;

    bf16x8 zf;
#pragma unroll
    for (int i = 0; i < 8; ++i) zf[i] = (__bf16)0.0f;
    const f32x4 zacc = {0.f, 0.f, 0.f, 0.f};

    // ---- stage Xs[c][n] bf16 (x transposed), zero-pad n=80..95 ----
    {
        const float* xb = x + (size_t)b * (N_TOK * C_CH);
        for (int u = tid; u < 10240; u += 512) {
            int np = u >> 8, c = u & 255;
            float a0 = xb[(2 * np) * C_CH + c];
            float a1 = xb[(2 * np + 1) * C_CH + c];
            unsigned int pk = (unsigned int)bfb(a0) | ((unsigned int)bfb(a1) << 16);
            *(unsigned int*)(smem + XS_OFF + c * 208 + np * 4) = pk;
        }
        for (int u = tid; u < 2048; u += 512) {
            int c = u >> 3, np = u & 7;
            *(unsigned int*)(smem + XS_OFF + c * 208 + 160 + np * 4) = 0u;
        }
    }

    for (int hg = 0; hg < 4; ++hg) {
        __syncthreads();   // Xs ready (hg=0); prev attention done (hg>0)

        // ---- stage bias-table columns for this head pair ----
        for (int i = tid; i < 2 * TBL_R; i += 512) {
            int hl = (i >= TBL_R) ? 1 : 0;
            int r = i - hl * TBL_R;
            *(float*)(smem + BT_OFF + (hl * 768 + r) * 4) = btT[(hg * 2 + hl) * TBL_R + r];
        }

        // ---- qkv GEMM: D[dd][c] per (s,hl) tile-row, K = n (80, pad 96) ----
        for (int sh = 0; sh < 6; ++sh) {
            int s = sh >> 1, hl = sh & 1, h = hg * 2 + hl;
            // A fragments (W rows), 3 K-steps; row j = s*80 + h*10 + m (m = dd)
            bf16x8 af[3];
            const float* wrow = w_qkv + (s * 80 + h * 10 + m) * 80;
#pragma unroll
            for (int ks = 0; ks < 3; ++ks) {
                bf16x8 f = zf;
                bool valid = (m < 10) && !(ks == 2 && g >= 2);
                if (valid) {
                    const float* p = wrow + ks * 32 + g * 8;
                    float4 l4 = *(const float4*)p;
                    float4 h4 = *(const float4*)(p + 4);
                    f[0] = (__bf16)l4.x; f[1] = (__bf16)l4.y; f[2] = (__bf16)l4.z; f[3] = (__bf16)l4.w;
                    f[4] = (__bf16)h4.x; f[5] = (__bf16)h4.y; f[6] = (__bf16)h4.z; f[7] = (__bf16)h4.w;
                }
                af[ks] = f;
            }
            // per-lane bias for output rows dd = 4g+r
            float bias_r[4];
#pragma unroll
            for (int r = 0; r < 4; ++r) {
                int dd = 4 * g + r;
                float bv = 0.f;
                if (dd < 10) {
                    if (s == 0) bv = q_bias[h * 10 + dd];
                    else if (s == 2) bv = v_bias[h * 10 + dd];
                }
                bias_r[r] = bv;
            }
#pragma unroll
            for (int ct2 = 0; ct2 < 2; ++ct2) {
                int ct = w + ct2 * 8;
                f32x4 acc = zacc;
#pragma unroll
                for (int ks = 0; ks < 3; ++ks) {
                    bf16x8 bfr = *(const bf16x8*)(smem + XS_OFF + (16 * ct + m) * 208 + ks * 64 + g * 16);
                    acc = __builtin_amdgcn_mfma_f32_16x16x32_bf16(af[ks], bfr, acc, 0, 0, 0);
                }
                int c = 16 * ct + m;
#pragma unroll
                for (int r = 0; r < 4; ++r) acc[r] += bias_r[r];
                if (s < 2) {
                    float ss = acc[0]*acc[0] + acc[1]*acc[1] + acc[2]*acc[2] + acc[3]*acc[3];
                    ss += __shfl_xor(ss, 16);
                    ss += __shfl_xor(ss, 32);
                    float inv = 1.f / (sqrtf(ss) + EPS_);
                    ull pk = (ull)bfb(acc[0] * inv) | ((ull)bfb(acc[1] * inv) << 16)
                           | ((ull)bfb(acc[2] * inv) << 32) | ((ull)bfb(acc[3] * inv) << 48);
                    if (s == 0) *(ull*)(smem + QH_OFF + (hl * 256 + c) * 32 + g * 8) = pk;
                    else        *(ull*)(smem + KH_OFF + (hl * 256 + c) * 48 + g * 8) = pk;
                } else {
#pragma unroll
                    for (int r = 0; r < 4; ++r) {
                        int dd = 4 * g + r;
                        *(__hip_bfloat16*)(smem + VT_OFF + (hl * 16 + dd) * 528 + c * 2) =
                            __float2bfloat16(acc[r]);
                    }
                }
            }
        }
        __syncthreads();   // Q/K/V + bt ready

        // ---- attention: wave -> head hl2 = w>>2, rows0 = (w&3)*64 ----
        const int hl2 = w >> 2, h2 = hg * 2 + hl2;
        const int rows0 = (w & 3) * 64;
        const char* QhB = smem + QH_OFF + hl2 * 256 * 32;
        const char* KhB = smem + KH_OFF + hl2 * 256 * 48;
        const char* VtB = smem + VT_OFF + hl2 * 16 * 528;
        const float* btl = (const float*)(smem + BT_OFF) + hl2 * 768;
        char* PsB = smem + PS_OFF + w * 5120;

        bf16x8 qf[4];
#pragma unroll
        for (int t = 0; t < 4; ++t) {
            bf16x8 f = zf;
            if (lane < 32) f = *(const bf16x8*)(QhB + (rows0 + t * 16 + m) * 32 + g * 16);
            qf[t] = f;
        }
        int cterm[4][4];
#pragma unroll
        for (int t = 0; t < 4; ++t)
#pragma unroll
            for (int r = 0; r < 4; ++r) {
                int cc = rows0 + t * 16 + 4 * g + r;
                cterm[t][r] = 3 * (cc >> 1) + (cc & 1) + 382;
            }
        const int eterm_m = 3 * (m >> 1) + (m & 1);

        f32x4 Oacc[4];
#pragma unroll
        for (int t = 0; t < 4; ++t) Oacc[t] = zacc;
        float s_part[4][4];
#pragma unroll
        for (int t = 0; t < 4; ++t)
#pragma unroll
            for (int r = 0; r < 4; ++r) s_part[t][r] = 0.f;

        for (int e0 = 0; e0 < C_CH; e0 += 32) {
            bf16x8 kf[2];
#pragma unroll
            for (int et = 0; et < 2; ++et) {
                bf16x8 f = zf;
                if (lane < 32) f = *(const bf16x8*)(KhB + (e0 + et * 16 + m) * 48 + g * 16);
                kf[et] = f;
            }
            f32x4 sacc[4][2];
#pragma unroll
            for (int t = 0; t < 4; ++t)
#pragma unroll
                for (int et = 0; et < 2; ++et)
                    sacc[t][et] = __builtin_amdgcn_mfma_f32_16x16x32_bf16(qf[t], kf[et], zacc, 0, 0, 0);
#pragma unroll
            for (int et = 0; et < 2; ++et) {
                int eterm = 3 * ((e0 + et * 16) >> 1) + eterm_m;
#pragma unroll
                for (int t = 0; t < 4; ++t)
#pragma unroll
                    for (int r = 0; r < 4; ++r) {
                        float bias2 = btl[cterm[t][r] - eterm];
                        float p = exp2f(fmaf(sacc[t][et][r], L2E, bias2));
                        s_part[t][r] += p;
                        *(__hip_bfloat16*)(PsB + (t * 16 + 4 * g + r) * 80 + (et * 16 + m) * 2) =
                            __float2bfloat16(p);
                    }
            }
            bf16x8 vf = *(const bf16x8*)(VtB + m * 528 + e0 * 2 + g * 16);
#pragma unroll
            for (int t = 0; t < 4; ++t) {
                bf16x8 pf = *(const bf16x8*)(PsB + (t * 16 + m) * 80 + g * 16);
                Oacc[t] = __builtin_amdgcn_mfma_f32_16x16x32_bf16(pf, vf, Oacc[t], 0, 0, 0);
            }
        }

        float rinv[4][4];
#pragma unroll
        for (int t = 0; t < 4; ++t)
#pragma unroll
            for (int r = 0; r < 4; ++r) {
                float s = s_part[t][r];
                s += __shfl_xor(s, 1);
                s += __shfl_xor(s, 2);
                s += __shfl_xor(s, 4);
                s += __shfl_xor(s, 8);
                rinv[t][r] = 1.f / s;
            }
        if (m < 10) {
            unsigned int* op = out2 + ((size_t)b * 80 + h2 * 10 + m) * 256;
#pragma unroll
            for (int t = 0; t < 4; ++t) {
                unsigned int wd[4];
#pragma unroll
                for (int r = 0; r < 4; ++r) {
                    float v = Oacc[t][r] * rinv[t][r];
                    unsigned short hi = bfb(v);
                    float lo = v - bf2f(hi);
                    wd[r] = (unsigned int)hi | ((unsigned int)bfb(lo) << 16);
                }
                *(uint4*)(op + rows0 + t * 16 + 4 * g) =
                    make_uint4(wd[0], wd[1], wd[2], wd[3]);
            }
        }
    }
}

// ---------------- Kernel 3: proj MFMA (K=160 hi/lo interleave), in-place ------
__global__ __launch_bounds__(512, 2) void proj_kernel(const unsigned int* __restrict__ out2,
                                                      const float* __restrict__ proj_w,
                                                      const float* __restrict__ proj_b,
                                                      float* __restrict__ out)
{
    __shared__ __align__(16) char smem[112896];  // Blds[256][168] + Wdup[80][168]
    const int tid = threadIdx.x, b = blockIdx.x;
    const int lane = tid & 63, w = tid >> 6;
    const int g = lane >> 4, m = lane & 15;

    const unsigned int* src = out2 + (size_t)b * (80 * 256);
    for (int u = tid; u < 80 * 256; u += 512) {
        int n = u >> 8, c = u & 255;
        *(unsigned int*)(smem + c * 336 + n * 4) = src[u];
    }
    for (int u = tid; u < 6400; u += 512) {
        int no = u / 80, n = u - no * 80;
        unsigned int wb = bfb(proj_w[u]);
        *(unsigned int*)(smem + 86016 + no * 336 + n * 4) = wb | (wb << 16);
    }
    __syncthreads();

    const f32x4 zacc = {0.f, 0.f, 0.f, 0.f};
    for (int tt = w; tt < 80; tt += 8) {
        int nt = tt >> 4, ct = tt & 15;
        f32x4 acc = zacc;
#pragma unroll
        for (int ks = 0; ks < 5; ++ks) {
            bf16x8 afr = *(const bf16x8*)(smem + 86016 + (nt * 16 + m) * 336 + ks * 64 + g * 16);
            bf16x8 bfr = *(const bf16x8*)(smem + (16 * ct + m) * 336 + ks * 64 + g * 16);
            acc = __builtin_amdgcn_mfma_f32_16x16x32_bf16(afr, bfr, acc, 0, 0, 0);
        }
        int cc = 16 * ct + m;
        float* dst = out + (size_t)b * (80 * 256) + cc;
#pragma unroll
        for (int r = 0; r < 4; ++r) {
            int no = nt * 16 + 4 * g + r;
            dst[no * 256] = acc[r] + proj_b[no];
        }
    }
}

extern "C" void kernel_launch(void* const* d_in, const int* in_sizes, int n_in,
                              void* d_out, int out_size, void* d_ws, size_t ws_size,
                              hipStream_t stream) {
    const float* x        = (const float*)d_in[0];
    const float* w_qkv    = (const float*)d_in[1];
    const float* q_bias   = (const float*)d_in[2];
    const float* v_bias   = (const float*)d_in[3];
    const float* w1       = (const float*)d_in[4];
    const float* b1       = (const float*)d_in[5];
    const float* w2       = (const float*)d_in[6];
    const float* proj_w   = (const float*)d_in[7];
    const float* proj_b   = (const float*)d_in[8];
    const float* table    = (const float*)d_in[9];
    float* out = (float*)d_out;

    float* btT = (float*)d_ws;   // [8][765] f32, 24.5 KB

    cpb_kernel<<<TBL_R, 64, 0, stream>>>(table, w1, b1, w2, btT);
    // mega writes hi/lo bf16 word-pairs into d_out ([b][80][256] u32 words);
    // proj re-reads them (full block staging before any store -> in-place safe)
    // and overwrites d_out with the final f32 result.
    mega_kernel<<<B_SZ, 512, 0, stream>>>(x, w_qkv, q_bias, v_bias, btT,
                                          (unsigned int*)d_out);
    proj_kernel<<<B_SZ, 512, 0, stream>>>((const unsigned int*)d_out, proj_w, proj_b, out);
}

// Round 5
// 102.444 us; speedup vs baseline: 1.8383x; 1.3016x over previous
//
#include <hip/hip_runtime.h>
#include <hip/hip_bf16.h>

// GroupAttention fully-MFMA, swapped-QK softmax with immediate-offset bias gather,
// MFMA row-sums (ones-row in V^T), LDS-staged W. B=256, N=80, C=256, H=8, hd=10.

#define B_SZ   256
#define N_TOK  80
#define C_CH   256
#define RPE_H  512
#define TBL_R  765
#define EPS_   5e-5f
#define L2E    1.44269504088896f

typedef __bf16 bf16x8 __attribute__((ext_vector_type(8)));
typedef float  f32x4  __attribute__((ext_vector_type(4)));
typedef unsigned long long ull;

// LDS byte offsets (mega kernel), total 158,208 <= 163,840
#define XS_OFF 0        // Xs[256][104] bf16, row stride 208 B (53,248)
#define QH_OFF 53248    // Qh[2][256][16] bf16, row stride 32 B (16,384)
#define KH_OFF 69632    // Kh[2][256][24] bf16, row stride 48 B (24,576)
#define VT_OFF 94208    // Vt[2][16][264] bf16, row stride 528 B (16,896)
#define PS_OFF 111104   // attn: Ps[8 waves][64][40] bf16 (40,960); qkv: Wl[96] rows, 192 B stride
#define WL_OFF PS_OFF
#define BT_OFF 152064   // btl[2][768] f32, REVERSED table (6,144)
#define SMEM_TOT 158208

__device__ inline unsigned short bfb(float f) {
    __hip_bfloat16 h = __float2bfloat16(f);
    return reinterpret_cast<unsigned short&>(h);
}
__device__ inline float bf2f(unsigned short u) {
    unsigned int w = ((unsigned int)u) << 16;
    return __uint_as_float(w);
}
__device__ inline unsigned int cvtpk(float lo, float hi) {
    unsigned int r;
    asm("v_cvt_pk_bf16_f32 %0, %1, %2" : "=v"(r) : "v"(lo), "v"(hi));
    return r;
}

// ---------------- Kernel 1: CPB MLP -> btT[h][765] = 16*sigmoid(mlp)*log2(e) ----
__global__ __launch_bounds__(64) void cpb_kernel(const float* __restrict__ table,
                                                 const float* __restrict__ w1,
                                                 const float* __restrict__ b1,
                                                 const float* __restrict__ w2,
                                                 float* __restrict__ btT)
{
    int r = blockIdx.x;
    int l = threadIdx.x;
    float t0 = table[r * 2 + 0];
    float t1 = table[r * 2 + 1];
    float part[8];
#pragma unroll
    for (int h = 0; h < 8; ++h) part[h] = 0.f;
    for (int j = l; j < RPE_H; j += 64) {
        float hv = fmaf(t0, w1[j * 2 + 0], fmaf(t1, w1[j * 2 + 1], b1[j]));
        hv = fmaxf(hv, 0.f);
#pragma unroll
        for (int h = 0; h < 8; ++h)
            part[h] = fmaf(hv, w2[h * RPE_H + j], part[h]);
    }
#pragma unroll
    for (int h = 0; h < 8; ++h) {
#pragma unroll
        for (int off = 32; off > 0; off >>= 1)
            part[h] += __shfl_xor(part[h], off, 64);
    }
    if (l == 0) {
#pragma unroll
        for (int h = 0; h < 8; ++h)
            btT[h * TBL_R + r] = L2E * 16.f / (1.f + __expf(-part[h]));
    }
}

// ---------------- Kernel 2: mega (per b): qkv MFMA GEMM + attention ----------
__global__ __launch_bounds__(512, 2) void mega_kernel(const float* __restrict__ x,
                                                      const float* __restrict__ w_qkv,
                                                      const float* __restrict__ q_bias,
                                                      const float* __restrict__ v_bias,
                                                      const float* __restrict__ btT,
                                                      unsigned int* __restrict__ out2)
{
    __shared__ __align__(16) char smem[SMEM_TOT];
    const int tid = threadIdx.x;
    const int b = blockIdx.x;
    const int lane = tid & 63, w = tid >> 6;
    const int g = lane >> 4, m = lane & 15;

    bf16x8 zf;
#pragma unroll
    for (int i = 0; i < 8; ++i) zf[i] = (__bf16)0.0f;
    const f32x4 zacc = {0.f, 0.f, 0.f, 0.f};

    // ---- stage Xs[c][n] bf16 (x transposed), zero-pad n=80..95 ----
    {
        const float* xb = x + (size_t)b * (N_TOK * C_CH);
        for (int u = tid; u < 10240; u += 512) {
            int np = u >> 8, c = u & 255;
            float a0 = xb[(2 * np) * C_CH + c];
            float a1 = xb[(2 * np + 1) * C_CH + c];
            unsigned int pk = (unsigned int)bfb(a0) | ((unsigned int)bfb(a1) << 16);
            *(unsigned int*)(smem + XS_OFF + c * 208 + np * 4) = pk;
        }
        for (int u = tid; u < 2048; u += 512) {
            int c = u >> 3, np = u & 7;
            *(unsigned int*)(smem + XS_OFF + c * 208 + 160 + np * 4) = 0u;
        }
    }

    for (int hg = 0; hg < 4; ++hg) {
        __syncthreads();   // Xs ready (hg=0); prev attention done (Ps/Wl, btl free)

        // ---- stage W rows (bf16, zeroed m>=10, zeroed k-tail) + reversed bt ----
        // Wl: 96 rows x 192 B (16-aligned). Words 0..39 = w values, 40..47 = 0.
        for (int u = tid; u < 96 * 48; u += 512) {
            int ri = u / 48, np = u - ri * 48;     // ri = sh*16 + m_
            int m_ = ri & 15, sh = ri >> 4;
            unsigned int val = 0u;
            if (m_ < 10 && np < 40) {
                int s = sh >> 1, hl = sh & 1;
                const float* wr = w_qkv + ((s * 80) + (hg * 2 + hl) * 10 + m_) * 80 + 2 * np;
                val = (unsigned int)bfb(wr[0]) | ((unsigned int)bfb(wr[1]) << 16);
            }
            *(unsigned int*)(smem + WL_OFF + ri * 192 + np * 4) = val;
        }
        for (int i = tid; i < 2 * TBL_R; i += 512) {
            int hl = (i >= TBL_R) ? 1 : 0;
            int r = i - hl * TBL_R;
            *(float*)(smem + BT_OFF + (hl * 768 + r) * 4) =
                btT[(hg * 2 + hl) * TBL_R + (764 - r)];
        }
        __syncthreads();   // W/bt staged

        // ---- qkv GEMM: D[dd][c] per (s,hl), K = n (80, pad 96) ----
        for (int sh = 0; sh < 6; ++sh) {
            int s = sh >> 1, hl = sh & 1, h = hg * 2 + hl;
            const char* wrow = smem + WL_OFF + (sh * 16 + m) * 192;
            bf16x8 af[3];
#pragma unroll
            for (int ks = 0; ks < 3; ++ks)
                af[ks] = *(const bf16x8*)(wrow + ks * 64 + g * 16);  // tail k>=80 reads zeros
            float bias_r[4];
#pragma unroll
            for (int r = 0; r < 4; ++r) {
                int dd = 4 * g + r;
                float bv = 0.f;
                if (dd < 10) {
                    if (s == 0) bv = q_bias[h * 10 + dd];
                    else if (s == 2) bv = v_bias[h * 10 + dd];
                }
                bias_r[r] = bv;
            }
#pragma unroll
            for (int ct2 = 0; ct2 < 2; ++ct2) {
                int ct = w + ct2 * 8;
                f32x4 acc = zacc;
#pragma unroll
                for (int ks = 0; ks < 3; ++ks) {
                    bf16x8 bfr = *(const bf16x8*)(smem + XS_OFF + (16 * ct + m) * 208 + ks * 64 + g * 16);
                    acc = __builtin_amdgcn_mfma_f32_16x16x32_bf16(af[ks], bfr, acc, 0, 0, 0);
                }
                int c = 16 * ct + m;
#pragma unroll
                for (int r = 0; r < 4; ++r) acc[r] += bias_r[r];
                if (s < 2) {
                    float ss = acc[0]*acc[0] + acc[1]*acc[1] + acc[2]*acc[2] + acc[3]*acc[3];
                    ss += __shfl_xor(ss, 16);
                    ss += __shfl_xor(ss, 32);
                    float inv = 1.f / (sqrtf(ss) + EPS_);
                    ull pk = (ull)bfb(acc[0] * inv) | ((ull)bfb(acc[1] * inv) << 16)
                           | ((ull)bfb(acc[2] * inv) << 32) | ((ull)bfb(acc[3] * inv) << 48);
                    if (s == 0) *(ull*)(smem + QH_OFF + (hl * 256 + c) * 32 + g * 8) = pk;
                    else        *(ull*)(smem + KH_OFF + (hl * 256 + c) * 48 + g * 8) = pk;
                } else {
#pragma unroll
                    for (int r = 0; r < 4; ++r) {
                        int dd = 4 * g + r;
                        float vv = acc[r];
                        if (r == 2) vv = (g == 2) ? 1.0f : vv;   // V^T row d=10 := 1 (row-sum trick)
                        *(__hip_bfloat16*)(smem + VT_OFF + (hl * 16 + dd) * 528 + c * 2) =
                            __float2bfloat16(vv);
                    }
                }
            }
        }
        __syncthreads();   // Q/K/V ready; Wl reads done -> Ps may overwrite

        // ---- attention: wave -> head hl2 = w>>2, c-rows rows0 = (w&3)*64 ----
        const int hl2 = w >> 2, h2 = hg * 2 + hl2;
        const int rows0 = (w & 3) * 64;
        const char* QhB = smem + QH_OFF + hl2 * (256 * 32);
        const char* KhB = smem + KH_OFF + hl2 * (256 * 48);
        const char* VtB = smem + VT_OFF + hl2 * (16 * 528);
        const float* btl = (const float*)(smem + BT_OFF) + hl2 * 768;
        char* PsB = smem + PS_OFF + w * 5120;

        bf16x8 qf[4];
#pragma unroll
        for (int t = 0; t < 4; ++t) {
            bf16x8 f = zf;
            if (lane < 32) f = *(const bf16x8*)(QhB + (rows0 + t * 16 + m) * 32 + g * 16);
            qf[t] = f;
        }
        // reversed-table bias base pointers: j = cpart(t,lane) + 48*e0i + 24*et + {0,1,3,4}[r]
        const int lane_cpart = 382 - 3 * (m >> 1) - (m & 1) + 6 * g;
        const float* btp[4];
#pragma unroll
        for (int t = 0; t < 4; ++t)
            btp[t] = btl + (lane_cpart - 3 * ((rows0 + t * 16) >> 1));

        f32x4 Oacc[4];
#pragma unroll
        for (int t = 0; t < 4; ++t) Oacc[t] = zacc;

#pragma unroll
        for (int e0i = 0; e0i < 8; ++e0i) {
            const int e0 = e0i * 32;
            bf16x8 kf[2];
#pragma unroll
            for (int et = 0; et < 2; ++et) {
                bf16x8 f = zf;
                if (lane < 32) f = *(const bf16x8*)(KhB + (e0 + et * 16 + m) * 48 + g * 16);
                kf[et] = f;
            }
            // S^T tiles: rows e = e0+et*16+4g+r, cols c = rows0+t*16+m
            f32x4 st[2][4];
#pragma unroll
            for (int et = 0; et < 2; ++et)
#pragma unroll
                for (int t = 0; t < 4; ++t)
                    st[et][t] = __builtin_amdgcn_mfma_f32_16x16x32_bf16(kf[et], qf[t], zacc, 0, 0, 0);
            // softmax numerator: bias via imm-offset ds_read, pack via cvt_pk, b64 store
#pragma unroll
            for (int et = 0; et < 2; ++et) {
#pragma unroll
                for (int t = 0; t < 4; ++t) {
                    const float* bp = btp[t] + 48 * e0i + 24 * et;
                    float p0 = exp2f(fmaf(st[et][t][0], L2E, bp[0]));
                    float p1 = exp2f(fmaf(st[et][t][1], L2E, bp[1]));
                    float p2 = exp2f(fmaf(st[et][t][2], L2E, bp[3]));
                    float p3 = exp2f(fmaf(st[et][t][3], L2E, bp[4]));
                    unsigned int w0 = cvtpk(p0, p1);
                    unsigned int w1 = cvtpk(p2, p3);
                    *(ull*)(PsB + (t * 16 + m) * 80 + et * 32 + g * 8) =
                        (ull)w0 | ((ull)w1 << 32);
                }
            }
            // PV over this 32-e chunk (d=10 column accumulates row sums)
            bf16x8 vf = *(const bf16x8*)(VtB + m * 528 + e0 * 2 + g * 16);
#pragma unroll
            for (int t = 0; t < 4; ++t) {
                bf16x8 pf = *(const bf16x8*)(PsB + (t * 16 + m) * 80 + g * 16);
                Oacc[t] = __builtin_amdgcn_mfma_f32_16x16x32_bf16(pf, vf, Oacc[t], 0, 0, 0);
            }
        }

        // row sums live in column d=10 (lane m==10 of each g-group)
        float rinv[4][4];
#pragma unroll
        for (int t = 0; t < 4; ++t)
#pragma unroll
            for (int r = 0; r < 4; ++r)
                rinv[t][r] = 1.f / __shfl(Oacc[t][r], (lane & 48) + 10, 64);

        if (m < 10) {
            unsigned int* op = out2 + ((size_t)b * 80 + h2 * 10 + m) * 256;
#pragma unroll
            for (int t = 0; t < 4; ++t) {
                unsigned int wd[4];
#pragma unroll
                for (int r = 0; r < 4; ++r) {
                    float v = Oacc[t][r] * rinv[t][r];
                    unsigned short hi = bfb(v);
                    float lo = v - bf2f(hi);
                    wd[r] = (unsigned int)hi | ((unsigned int)bfb(lo) << 16);
                }
                *(uint4*)(op + rows0 + t * 16 + 4 * g) =
                    make_uint4(wd[0], wd[1], wd[2], wd[3]);
            }
        }
    }
}

// ---------------- Kernel 3: proj MFMA (K=160 hi/lo interleave), in-place ------
__global__ __launch_bounds__(512, 2) void proj_kernel(const unsigned int* __restrict__ out2,
                                                      const float* __restrict__ proj_w,
                                                      const float* __restrict__ proj_b,
                                                      float* __restrict__ out)
{
    __shared__ __align__(16) char smem[112896];  // Blds[256][168] + Wdup[80][168]
    const int tid = threadIdx.x, b = blockIdx.x;
    const int lane = tid & 63, w = tid >> 6;
    const int g = lane >> 4, m = lane & 15;

    const unsigned int* src = out2 + (size_t)b * (80 * 256);
    for (int u = tid; u < 80 * 256; u += 512) {
        int n = u >> 8, c = u & 255;
        *(unsigned int*)(smem + c * 336 + n * 4) = src[u];
    }
    for (int u = tid; u < 6400; u += 512) {
        int no = u / 80, n = u - no * 80;
        unsigned int wb = bfb(proj_w[u]);
        *(unsigned int*)(smem + 86016 + no * 336 + n * 4) = wb | (wb << 16);
    }
    __syncthreads();

    const f32x4 zacc = {0.f, 0.f, 0.f, 0.f};
    for (int tt = w; tt < 80; tt += 8) {
        int nt = tt >> 4, ct = tt & 15;
        f32x4 acc = zacc;
#pragma unroll
        for (int ks = 0; ks < 5; ++ks) {
            bf16x8 afr = *(const bf16x8*)(smem + 86016 + (nt * 16 + m) * 336 + ks * 64 + g * 16);
            bf16x8 bfr = *(const bf16x8*)(smem + (16 * ct + m) * 336 + ks * 64 + g * 16);
            acc = __builtin_amdgcn_mfma_f32_16x16x32_bf16(afr, bfr, acc, 0, 0, 0);
        }
        int cc = 16 * ct + m;
        float* dst = out + (size_t)b * (80 * 256) + cc;
#pragma unroll
        for (int r = 0; r < 4; ++r) {
            int no = nt * 16 + 4 * g + r;
            dst[no * 256] = acc[r] + proj_b[no];
        }
    }
}

extern "C" void kernel_launch(void* const* d_in, const int* in_sizes, int n_in,
                              void* d_out, int out_size, void* d_ws, size_t ws_size,
                              hipStream_t stream) {
    const float* x        = (const float*)d_in[0];
    const float* w_qkv    = (const float*)d_in[1];
    const float* q_bias   = (const float*)d_in[2];
    const float* v_bias   = (const float*)d_in[3];
    const float* w1       = (const float*)d_in[4];
    const float* b1       = (const float*)d_in[5];
    const float* w2       = (const float*)d_in[6];
    const float* proj_w   = (const float*)d_in[7];
    const float* proj_b   = (const float*)d_in[8];
    const float* table    = (const float*)d_in[9];
    float* out = (float*)d_out;

    float* btT = (float*)d_ws;   // [8][765] f32, 24.5 KB

    cpb_kernel<<<TBL_R, 64, 0, stream>>>(table, w1, b1, w2, btT);
    // mega writes hi/lo bf16 word-pairs into d_out ([b][80][256] u32 words);
    // proj re-reads them (full block staging before any store -> in-place safe)
    // and overwrites d_out with the final f32 result.
    mega_kernel<<<B_SZ, 512, 0, stream>>>(x, w_qkv, q_bias, v_bias, btT,
                                          (unsigned int*)d_out);
    proj_kernel<<<B_SZ, 512, 0, stream>>>((const unsigned int*)d_out, proj_w, proj_b, out);
}

// Round 6
// 93.416 us; speedup vs baseline: 2.0159x; 1.0966x over previous
//
#include <hip/hip_runtime.h>
#include <hip/hip_bf16.h>

// GroupAttention: split-kernel MFMA pipeline. B=256, N=80, C=256, H=8, hd=10.
// qkv_kernel (per b, high occ) -> attn2_kernel (per (b,h), 23KB LDS, 4 w/SIMD)
// -> proj_kernel2. Q lives inside d_out (slot each attn block later overwrites).
// Fallback to fused mega_kernel if ws_size < 32MB+32KB.

#define B_SZ   256
#define N_TOK  80
#define C_CH   256
#define RPE_H  512
#define TBL_R  765
#define EPS_   5e-5f
#define L2E    1.44269504088896f

typedef __bf16 bf16x8 __attribute__((ext_vector_type(8)));
typedef float  f32x4  __attribute__((ext_vector_type(4)));
typedef unsigned long long ull;

__device__ inline unsigned int bfb(float f) {
    __hip_bfloat16 h = __float2bfloat16(f);
    return (unsigned int)reinterpret_cast<unsigned short&>(h);
}
__device__ inline float bf2f(unsigned short u) {
    unsigned int w = ((unsigned int)u) << 16;
    return __uint_as_float(w);
}
__device__ inline unsigned int cvtpk(float lo, float hi) {
    unsigned int r;
    asm("v_cvt_pk_bf16_f32 %0, %1, %2" : "=v"(r) : "v"(lo), "v"(hi));
    return r;
}

// ---------------- Kernel 1: CPB MLP -> btT[h][765] = 16*sigmoid(mlp)*log2(e) ----
__global__ __launch_bounds__(64) void cpb_kernel(const float* __restrict__ table,
                                                 const float* __restrict__ w1,
                                                 const float* __restrict__ b1,
                                                 const float* __restrict__ w2,
                                                 float* __restrict__ btT)
{
    int r = blockIdx.x;
    int l = threadIdx.x;
    float t0 = table[r * 2 + 0];
    float t1 = table[r * 2 + 1];
    float part[8];
#pragma unroll
    for (int h = 0; h < 8; ++h) part[h] = 0.f;
    for (int j = l; j < RPE_H; j += 64) {
        float hv = fmaf(t0, w1[j * 2 + 0], fmaf(t1, w1[j * 2 + 1], b1[j]));
        hv = fmaxf(hv, 0.f);
#pragma unroll
        for (int h = 0; h < 8; ++h)
            part[h] = fmaf(hv, w2[h * RPE_H + j], part[h]);
    }
#pragma unroll
    for (int h = 0; h < 8; ++h) {
#pragma unroll
        for (int off = 32; off > 0; off >>= 1)
            part[h] += __shfl_xor(part[h], off, 64);
    }
    if (l == 0) {
#pragma unroll
        for (int h = 0; h < 8; ++h)
            btT[h * TBL_R + r] = L2E * 16.f / (1.f + __expf(-part[h]));
    }
}

// ---------------- Kernel 2a: qkv GEMM per b, write Q->d_out, K/V^T->ws --------
// Q layout (inside d_out): per (b,h) at byte off ((b*80+h*10)*1024): [256 c][16 d] bf16.
// K: ws, per (b,h) 8192B: [256 e][16 d] bf16.  V^T: ws, per (b,h) 8192B: [16 d][256 e],
// row d=10 = 1.0 (MFMA row-sum trick), rows 11..15 = 0.
__global__ __launch_bounds__(512, 4) void qkv_kernel(const float* __restrict__ x,
                                                     const float* __restrict__ w_qkv,
                                                     const float* __restrict__ q_bias,
                                                     const float* __restrict__ v_bias,
                                                     char* __restrict__ qout,
                                                     char* __restrict__ kbufc,
                                                     char* __restrict__ vbufc)
{
    __shared__ __align__(16) char smem[53248];   // Xs[256][104] bf16, stride 208B
    const int tid = threadIdx.x, b = blockIdx.x;
    const int lane = tid & 63, w = tid >> 6;
    const int g = lane >> 4, m = lane & 15;

    bf16x8 zf;
#pragma unroll
    for (int i = 0; i < 8; ++i) zf[i] = (__bf16)0.0f;
    const f32x4 zacc = {0.f, 0.f, 0.f, 0.f};

    // stage Xs[c][n] bf16 (x transposed), zero-pad n=80..95
    {
        const float* xb = x + (size_t)b * (N_TOK * C_CH);
        for (int u = tid; u < 10240; u += 512) {
            int np = u >> 8, c = u & 255;
            float a0 = xb[(2 * np) * C_CH + c];
            float a1 = xb[(2 * np + 1) * C_CH + c];
            *(unsigned int*)(smem + c * 208 + np * 4) = bfb(a0) | (bfb(a1) << 16);
        }
        for (int u = tid; u < 2048; u += 512) {
            int c = u >> 3, np = u & 7;
            *(unsigned int*)(smem + c * 208 + 160 + np * 4) = 0u;
        }
    }
    __syncthreads();

    // each wave owns 3 of the 24 (s,h) tile-rows; all 16 c-tiles
#pragma unroll 1
    for (int i3 = 0; i3 < 3; ++i3) {
        const int sh = w * 3 + i3;          // 0..23
        const int s = sh >> 3, h = sh & 7;
        const float* wrow = w_qkv + (s * 80 + h * 10 + m) * 80;
        bf16x8 af[3];
#pragma unroll
        for (int ks = 0; ks < 3; ++ks) {
            bf16x8 f = zf;
            bool valid = (m < 10) && !(ks == 2 && g >= 2);
            if (valid) {
                const float* p = wrow + ks * 32 + g * 8;
                float4 l4 = *(const float4*)p;
                float4 h4 = *(const float4*)(p + 4);
                f[0] = (__bf16)l4.x; f[1] = (__bf16)l4.y; f[2] = (__bf16)l4.z; f[3] = (__bf16)l4.w;
                f[4] = (__bf16)h4.x; f[5] = (__bf16)h4.y; f[6] = (__bf16)h4.z; f[7] = (__bf16)h4.w;
            }
            af[ks] = f;
        }
        float bias_r[4];
#pragma unroll
        for (int r = 0; r < 4; ++r) {
            int dd = 4 * g + r;
            float bv = 0.f;
            if (dd < 10) {
                if (s == 0) bv = q_bias[h * 10 + dd];
                else if (s == 2) bv = v_bias[h * 10 + dd];
            }
            bias_r[r] = bv;
        }
        char* qb = qout + ((size_t)b * 80 + h * 10) * 1024;
        char* kb = kbufc + ((size_t)b * 8 + h) * 8192;
        char* vb = vbufc + ((size_t)b * 8 + h) * 8192;

#pragma unroll 2
        for (int ct = 0; ct < 16; ++ct) {
            f32x4 acc = zacc;
#pragma unroll
            for (int ks = 0; ks < 3; ++ks) {
                bf16x8 bfr = *(const bf16x8*)(smem + (16 * ct + m) * 208 + ks * 64 + g * 16);
                acc = __builtin_amdgcn_mfma_f32_16x16x32_bf16(af[ks], bfr, acc, 0, 0, 0);
            }
            int c = 16 * ct + m;
#pragma unroll
            for (int r = 0; r < 4; ++r) acc[r] += bias_r[r];
            if (s < 2) {
                float ss = acc[0]*acc[0] + acc[1]*acc[1] + acc[2]*acc[2] + acc[3]*acc[3];
                ss += __shfl_xor(ss, 16);
                ss += __shfl_xor(ss, 32);
                float inv = 1.f / (sqrtf(ss) + EPS_);
                ull pk = (ull)bfb(acc[0] * inv) | ((ull)bfb(acc[1] * inv) << 16)
                       | ((ull)bfb(acc[2] * inv) << 32) | ((ull)bfb(acc[3] * inv) << 48);
                if (s == 0) *(ull*)(qb + c * 32 + g * 8) = pk;
                else        *(ull*)(kb + c * 32 + g * 8) = pk;
            } else {
#pragma unroll
                for (int r = 0; r < 4; ++r) {
                    int dd = 4 * g + r;
                    float vv = (dd == 10) ? 1.0f : acc[r];   // ones-row for row sums
                    *(__hip_bfloat16*)(vb + dd * 512 + c * 2) = __float2bfloat16(vv);
                }
            }
        }
    }
}

// ---------------- Kernel 2b: attention per (b,h): 23KB LDS, 4 waves ----------
__global__ __launch_bounds__(256, 4) void attn2_kernel(const char* qin,          // aliases out2!
                                                       const char* __restrict__ kbufc,
                                                       const char* __restrict__ vbufc,
                                                       const float* __restrict__ btT,
                                                       unsigned int* out2)       // aliases qin!
{
    __shared__ __align__(16) char smem[23552];   // bt[768] f32 + Ps[4][64][40] bf16
    const int tid = threadIdx.x;
    const int b = blockIdx.x >> 3, h = blockIdx.x & 7;
    const int lane = tid & 63, w = tid >> 6;
    const int g = lane >> 4, m = lane & 15;
    const int rows0 = w * 64;

    float* bt = (float*)smem;
    for (int i = tid; i < TBL_R; i += 256)
        bt[i] = btT[h * TBL_R + (764 - i)];       // reversed table
    char* PsB = smem + 3072 + w * 5120;

    const char* qb = qin + ((size_t)b * 80 + h * 10) * 1024;
    const char* kb = kbufc + ((size_t)b * 8 + h) * 8192;
    const char* vb = vbufc + ((size_t)b * 8 + h) * 8192;

    bf16x8 zf;
#pragma unroll
    for (int i = 0; i < 8; ++i) zf[i] = (__bf16)0.0f;
    const f32x4 zacc = {0.f, 0.f, 0.f, 0.f};

    bf16x8 qf[4];
#pragma unroll
    for (int t = 0; t < 4; ++t) {
        bf16x8 f = zf;
        if (lane < 32) f = *(const bf16x8*)(qb + (rows0 + t * 16 + m) * 32 + g * 16);
        qf[t] = f;
    }
    __syncthreads();   // bt ready

    // reversed-table bias bases: idx = cpart - 3*(c>>1 terms) + 48*e0i + 24*et + {0,1,3,4}[r]
    const int lane_cpart = 382 - 3 * (m >> 1) - (m & 1) + 6 * g;
    const float* btp[4];
#pragma unroll
    for (int t = 0; t < 4; ++t)
        btp[t] = bt + (lane_cpart - 3 * ((rows0 + t * 16) >> 1));

    f32x4 Oacc[4];
#pragma unroll
    for (int t = 0; t < 4; ++t) Oacc[t] = zacc;

#pragma unroll
    for (int e0i = 0; e0i < 8; ++e0i) {
        const int e0 = e0i * 32;
        bf16x8 kf[2];
#pragma unroll
        for (int et = 0; et < 2; ++et) {
            bf16x8 f = zf;
            if (lane < 32) f = *(const bf16x8*)(kb + (e0 + et * 16 + m) * 32 + g * 16);
            kf[et] = f;
        }
        // S^T tiles: rows e = e0+et*16+4g+r, cols c = rows0+t*16+m
        f32x4 st[2][4];
#pragma unroll
        for (int et = 0; et < 2; ++et)
#pragma unroll
            for (int t = 0; t < 4; ++t)
                st[et][t] = __builtin_amdgcn_mfma_f32_16x16x32_bf16(kf[et], qf[t], zacc, 0, 0, 0);
#pragma unroll
        for (int et = 0; et < 2; ++et) {
#pragma unroll
            for (int t = 0; t < 4; ++t) {
                const float* bp = btp[t] + 48 * e0i + 24 * et;
                float p0 = exp2f(fmaf(st[et][t][0], L2E, bp[0]));
                float p1 = exp2f(fmaf(st[et][t][1], L2E, bp[1]));
                float p2 = exp2f(fmaf(st[et][t][2], L2E, bp[3]));
                float p3 = exp2f(fmaf(st[et][t][3], L2E, bp[4]));
                unsigned int w0 = cvtpk(p0, p1);
                unsigned int w1 = cvtpk(p2, p3);
                *(ull*)(PsB + (t * 16 + m) * 80 + et * 32 + g * 8) =
                    (ull)w0 | ((ull)w1 << 32);
            }
        }
        bf16x8 vf = *(const bf16x8*)(vb + m * 512 + e0 * 2 + g * 16);
#pragma unroll
        for (int t = 0; t < 4; ++t) {
            bf16x8 pf = *(const bf16x8*)(PsB + (t * 16 + m) * 80 + g * 16);
            Oacc[t] = __builtin_amdgcn_mfma_f32_16x16x32_bf16(pf, vf, Oacc[t], 0, 0, 0);
        }
    }

    // row sums live in output column d=10
    float rinv[4][4];
#pragma unroll
    for (int t = 0; t < 4; ++t)
#pragma unroll
        for (int r = 0; r < 4; ++r)
            rinv[t][r] = 1.f / __shfl(Oacc[t][r], (lane & 48) + 10, 64);

    if (m < 10) {
        unsigned int* op = out2 + ((size_t)b * 80 + h * 10 + m) * 256;
#pragma unroll
        for (int t = 0; t < 4; ++t) {
            unsigned int wd[4];
#pragma unroll
            for (int r = 0; r < 4; ++r) {
                float v = Oacc[t][r] * rinv[t][r];
                unsigned short hi = (unsigned short)bfb(v);
                float lo = v - bf2f(hi);
                wd[r] = (unsigned int)hi | (bfb(lo) << 16);
            }
            *(uint4*)(op + rows0 + t * 16 + 4 * g) = make_uint4(wd[0], wd[1], wd[2], wd[3]);
        }
    }
}

// ---------------- Fallback: fused mega (R5, Wl stride 192->208 fix) -----------
#define XS_OFF 0
#define QH_OFF 53248
#define KH_OFF 69632
#define VT_OFF 94208
#define PS_OFF 111104
#define WL_OFF PS_OFF
#define BT_OFF 152064
#define SMEM_TOT 158208

__global__ __launch_bounds__(512, 2) void mega_kernel(const float* __restrict__ x,
                                                      const float* __restrict__ w_qkv,
                                                      const float* __restrict__ q_bias,
                                                      const float* __restrict__ v_bias,
                                                      const float* __restrict__ btT,
                                                      unsigned int* __restrict__ out2)
{
    __shared__ __align__(16) char smem[SMEM_TOT];
    const int tid = threadIdx.x;
    const int b = blockIdx.x;
    const int lane = tid & 63, w = tid >> 6;
    const int g = lane >> 4, m = lane & 15;

    bf16x8 zf;
#pragma unroll
    for (int i = 0; i < 8; ++i) zf[i] = (__bf16)0.0f;
    const f32x4 zacc = {0.f, 0.f, 0.f, 0.f};

    {
        const float* xb = x + (size_t)b * (N_TOK * C_CH);
        for (int u = tid; u < 10240; u += 512) {
            int np = u >> 8, c = u & 255;
            float a0 = xb[(2 * np) * C_CH + c];
            float a1 = xb[(2 * np + 1) * C_CH + c];
            *(unsigned int*)(smem + XS_OFF + c * 208 + np * 4) = bfb(a0) | (bfb(a1) << 16);
        }
        for (int u = tid; u < 2048; u += 512) {
            int c = u >> 3, np = u & 7;
            *(unsigned int*)(smem + XS_OFF + c * 208 + 160 + np * 4) = 0u;
        }
    }

    for (int hg = 0; hg < 4; ++hg) {
        __syncthreads();

        for (int u = tid; u < 96 * 52; u += 512) {
            int ri = u / 52, np = u - ri * 52;
            int m_ = ri & 15, sh = ri >> 4;
            unsigned int val = 0u;
            if (m_ < 10 && np < 40) {
                int s = sh >> 1, hl = sh & 1;
                const float* wr = w_qkv + ((s * 80) + (hg * 2 + hl) * 10 + m_) * 80 + 2 * np;
                val = bfb(wr[0]) | (bfb(wr[1]) << 16);
            }
            *(unsigned int*)(smem + WL_OFF + ri * 208 + np * 4) = val;
        }
        for (int i = tid; i < 2 * TBL_R; i += 512) {
            int hl = (i >= TBL_R) ? 1 : 0;
            int r = i - hl * TBL_R;
            *(float*)(smem + BT_OFF + (hl * 768 + r) * 4) =
                btT[(hg * 2 + hl) * TBL_R + (764 - r)];
        }
        __syncthreads();

        for (int sh = 0; sh < 6; ++sh) {
            int s = sh >> 1, hl = sh & 1, h = hg * 2 + hl;
            const char* wrow = smem + WL_OFF + (sh * 16 + m) * 208;
            bf16x8 af[3];
#pragma unroll
            for (int ks = 0; ks < 3; ++ks)
                af[ks] = *(const bf16x8*)(wrow + ks * 64 + g * 16);
            float bias_r[4];
#pragma unroll
            for (int r = 0; r < 4; ++r) {
                int dd = 4 * g + r;
                float bv = 0.f;
                if (dd < 10) {
                    if (s == 0) bv = q_bias[h * 10 + dd];
                    else if (s == 2) bv = v_bias[h * 10 + dd];
                }
                bias_r[r] = bv;
            }
#pragma unroll
            for (int ct2 = 0; ct2 < 2; ++ct2) {
                int ct = w + ct2 * 8;
                f32x4 acc = zacc;
#pragma unroll
                for (int ks = 0; ks < 3; ++ks) {
                    bf16x8 bfr = *(const bf16x8*)(smem + XS_OFF + (16 * ct + m) * 208 + ks * 64 + g * 16);
                    acc = __builtin_amdgcn_mfma_f32_16x16x32_bf16(af[ks], bfr, acc, 0, 0, 0);
                }
                int c = 16 * ct + m;
#pragma unroll
                for (int r = 0; r < 4; ++r) acc[r] += bias_r[r];
                if (s < 2) {
                    float ss = acc[0]*acc[0] + acc[1]*acc[1] + acc[2]*acc[2] + acc[3]*acc[3];
                    ss += __shfl_xor(ss, 16);
                    ss += __shfl_xor(ss, 32);
                    float inv = 1.f / (sqrtf(ss) + EPS_);
                    ull pk = (ull)bfb(acc[0] * inv) | ((ull)bfb(acc[1] * inv) << 16)
                           | ((ull)bfb(acc[2] * inv) << 32) | ((ull)bfb(acc[3] * inv) << 48);
                    if (s == 0) *(ull*)(smem + QH_OFF + (hl * 256 + c) * 32 + g * 8) = pk;
                    else        *(ull*)(smem + KH_OFF + (hl * 256 + c) * 48 + g * 8) = pk;
                } else {
#pragma unroll
                    for (int r = 0; r < 4; ++r) {
                        int dd = 4 * g + r;
                        float vv = acc[r];
                        if (r == 2) vv = (g == 2) ? 1.0f : vv;
                        *(__hip_bfloat16*)(smem + VT_OFF + (hl * 16 + dd) * 528 + c * 2) =
                            __float2bfloat16(vv);
                    }
                }
            }
        }
        __syncthreads();

        const int hl2 = w >> 2, h2 = hg * 2 + hl2;
        const int rows0 = (w & 3) * 64;
        const char* QhB = smem + QH_OFF + hl2 * (256 * 32);
        const char* KhB = smem + KH_OFF + hl2 * (256 * 48);
        const char* VtB = smem + VT_OFF + hl2 * (16 * 528);
        const float* btl = (const float*)(smem + BT_OFF) + hl2 * 768;
        char* PsB = smem + PS_OFF + w * 5120;

        bf16x8 qf[4];
#pragma unroll
        for (int t = 0; t < 4; ++t) {
            bf16x8 f = zf;
            if (lane < 32) f = *(const bf16x8*)(QhB + (rows0 + t * 16 + m) * 32 + g * 16);
            qf[t] = f;
        }
        const int lane_cpart = 382 - 3 * (m >> 1) - (m & 1) + 6 * g;
        const float* btp[4];
#pragma unroll
        for (int t = 0; t < 4; ++t)
            btp[t] = btl + (lane_cpart - 3 * ((rows0 + t * 16) >> 1));

        f32x4 Oacc[4];
#pragma unroll
        for (int t = 0; t < 4; ++t) Oacc[t] = zacc;

#pragma unroll
        for (int e0i = 0; e0i < 8; ++e0i) {
            const int e0 = e0i * 32;
            bf16x8 kf[2];
#pragma unroll
            for (int et = 0; et < 2; ++et) {
                bf16x8 f = zf;
                if (lane < 32) f = *(const bf16x8*)(KhB + (e0 + et * 16 + m) * 48 + g * 16);
                kf[et] = f;
            }
            f32x4 st[2][4];
#pragma unroll
            for (int et = 0; et < 2; ++et)
#pragma unroll
                for (int t = 0; t < 4; ++t)
                    st[et][t] = __builtin_amdgcn_mfma_f32_16x16x32_bf16(kf[et], qf[t], zacc, 0, 0, 0);
#pragma unroll
            for (int et = 0; et < 2; ++et) {
#pragma unroll
                for (int t = 0; t < 4; ++t) {
                    const float* bp = btp[t] + 48 * e0i + 24 * et;
                    float p0 = exp2f(fmaf(st[et][t][0], L2E, bp[0]));
                    float p1 = exp2f(fmaf(st[et][t][1], L2E, bp[1]));
                    float p2 = exp2f(fmaf(st[et][t][2], L2E, bp[3]));
                    float p3 = exp2f(fmaf(st[et][t][3], L2E, bp[4]));
                    unsigned int w0 = cvtpk(p0, p1);
                    unsigned int w1 = cvtpk(p2, p3);
                    *(ull*)(PsB + (t * 16 + m) * 80 + et * 32 + g * 8) =
                        (ull)w0 | ((ull)w1 << 32);
                }
            }
            bf16x8 vf = *(const bf16x8*)(VtB + m * 528 + e0 * 2 + g * 16);
#pragma unroll
            for (int t = 0; t < 4; ++t) {
                bf16x8 pf = *(const bf16x8*)(PsB + (t * 16 + m) * 80 + g * 16);
                Oacc[t] = __builtin_amdgcn_mfma_f32_16x16x32_bf16(pf, vf, Oacc[t], 0, 0, 0);
            }
        }

        float rinv[4][4];
#pragma unroll
        for (int t = 0; t < 4; ++t)
#pragma unroll
            for (int r = 0; r < 4; ++r)
                rinv[t][r] = 1.f / __shfl(Oacc[t][r], (lane & 48) + 10, 64);

        if (m < 10) {
            unsigned int* op = out2 + ((size_t)b * 80 + h2 * 10 + m) * 256;
#pragma unroll
            for (int t = 0; t < 4; ++t) {
                unsigned int wd[4];
#pragma unroll
                for (int r = 0; r < 4; ++r) {
                    float v = Oacc[t][r] * rinv[t][r];
                    unsigned short hi = (unsigned short)bfb(v);
                    float lo = v - bf2f(hi);
                    wd[r] = (unsigned int)hi | (bfb(lo) << 16);
                }
                *(uint4*)(op + rows0 + t * 16 + 4 * g) =
                    make_uint4(wd[0], wd[1], wd[2], wd[3]);
            }
        }
    }
}

// ---------------- Kernel 3: proj MFMA per (b, c-half), in-place safe ----------
__global__ __launch_bounds__(512, 2) void proj_kernel2(const unsigned int* __restrict__ out2,
                                                       const float* __restrict__ proj_w,
                                                       const float* __restrict__ proj_b,
                                                       float* __restrict__ out)
{
    __shared__ __align__(16) char smem[69888];  // Blds[128][336] + Wdup[80][336]
    const int tid = threadIdx.x;
    const int b = blockIdx.x >> 1, ch = blockIdx.x & 1;
    const int lane = tid & 63, w = tid >> 6;
    const int g = lane >> 4, m = lane & 15;

    const unsigned int* src = out2 + (size_t)b * (80 * 256) + ch * 128;
    for (int u = tid; u < 80 * 128; u += 512) {
        int n = u >> 7, cl = u & 127;
        *(unsigned int*)(smem + cl * 336 + n * 4) = src[n * 256 + cl];
    }
    for (int u = tid; u < 6400; u += 512) {
        int no = u / 80, n = u - no * 80;
        unsigned int wb = bfb(proj_w[u]);
        *(unsigned int*)(smem + 43008 + no * 336 + n * 4) = wb | (wb << 16);
    }
    __syncthreads();

    const f32x4 zacc = {0.f, 0.f, 0.f, 0.f};
    for (int tt = w; tt < 40; tt += 8) {
        int nt = tt >> 3, ct = tt & 7;
        f32x4 acc = zacc;
#pragma unroll
        for (int ks = 0; ks < 5; ++ks) {
            bf16x8 afr = *(const bf16x8*)(smem + 43008 + (nt * 16 + m) * 336 + ks * 64 + g * 16);
            bf16x8 bfr = *(const bf16x8*)(smem + (16 * ct + m) * 336 + ks * 64 + g * 16);
            acc = __builtin_amdgcn_mfma_f32_16x16x32_bf16(afr, bfr, acc, 0, 0, 0);
        }
        int cc = ch * 128 + 16 * ct + m;
        float* dst = out + (size_t)b * (80 * 256) + cc;
#pragma unroll
        for (int r = 0; r < 4; ++r) {
            int no = nt * 16 + 4 * g + r;
            dst[no * 256] = acc[r] + proj_b[no];
        }
    }
}

extern "C" void kernel_launch(void* const* d_in, const int* in_sizes, int n_in,
                              void* d_out, int out_size, void* d_ws, size_t ws_size,
                              hipStream_t stream) {
    const float* x        = (const float*)d_in[0];
    const float* w_qkv    = (const float*)d_in[1];
    const float* q_bias   = (const float*)d_in[2];
    const float* v_bias   = (const float*)d_in[3];
    const float* w1       = (const float*)d_in[4];
    const float* b1       = (const float*)d_in[5];
    const float* w2       = (const float*)d_in[6];
    const float* proj_w   = (const float*)d_in[7];
    const float* proj_b   = (const float*)d_in[8];
    const float* table    = (const float*)d_in[9];
    float* out = (float*)d_out;

    float* btT = (float*)d_ws;   // [8][765] f32 @ ws+0 (32KB slot)

    cpb_kernel<<<TBL_R, 64, 0, stream>>>(table, w1, b1, w2, btT);

    const size_t NEED = 32768ULL + 2ULL * 16777216ULL;  // btT + K(16MB) + V(16MB)
    if (ws_size >= NEED) {
        char* kbufc = (char*)d_ws + 32768;
        char* vbufc = kbufc + 16777216;
        // Q is written into d_out (each (b,h)'s 8KB inside the 10KB out2 slot
        // that the same attn2 block reads fully before overwriting).
        qkv_kernel<<<B_SZ, 512, 0, stream>>>(x, w_qkv, q_bias, v_bias,
                                             (char*)d_out, kbufc, vbufc);
        attn2_kernel<<<B_SZ * 8, 256, 0, stream>>>((const char*)d_out, kbufc, vbufc,
                                                   btT, (unsigned int*)d_out);
    } else {
        mega_kernel<<<B_SZ, 512, 0, stream>>>(x, w_qkv, q_bias, v_bias, btT,
                                              (unsigned int*)d_out);
    }
    proj_kernel2<<<B_SZ * 2, 512, 0, stream>>>((const unsigned int*)d_out,
                                               proj_w, proj_b, out);
}

// Round 8
// 84.220 us; speedup vs baseline: 2.2360x; 1.1092x over previous
//
#include <hip/hip_runtime.h>
#include <hip/hip_bf16.h>

// GroupAttention: split-kernel MFMA pipeline. B=256, N=80, C=256, H=8, hd=10.
// qkv_kernel (per b; Q pre-scaled by log2e) -> attn2_kernel (per (b,h); bias via
// MFMA C-operand, hw exp2 softmax) -> proj_kernel2.
// Q lives inside d_out (slot each attn block later overwrites).
// Fallback to fused mega_kernel if ws_size < 32MB+32KB.

#define B_SZ   256
#define N_TOK  80
#define C_CH   256
#define RPE_H  512
#define TBL_R  765
#define EPS_   5e-5f
#define L2E    1.44269504088896f

typedef __bf16 bf16x8 __attribute__((ext_vector_type(8)));
typedef float  f32x4  __attribute__((ext_vector_type(4)));
typedef unsigned long long ull;

__device__ inline unsigned int bfb(float f) {
    __hip_bfloat16 h = __float2bfloat16(f);
    return (unsigned int)reinterpret_cast<unsigned short&>(h);
}
__device__ inline float bf2f(unsigned short u) {
    unsigned int w = ((unsigned int)u) << 16;
    return __uint_as_float(w);
}
__device__ inline unsigned int cvtpk(float lo, float hi) {
    unsigned int r;
    asm("v_cvt_pk_bf16_f32 %0, %1, %2" : "=v"(r) : "v"(lo), "v"(hi));
    return r;
}
// hardware exp2: inputs bounded in [-2, 26] here (no denorm/overflow edge cases).
// Use the builtin so the compiler inserts the required TRANS->VALU wait state
// (raw single-instruction asm caused the R7 NaN: consumer read the result early).
#if defined(__has_builtin) && __has_builtin(__builtin_amdgcn_exp2f)
__device__ inline float vexp2(float x) { return __builtin_amdgcn_exp2f(x); }
#else
__device__ inline float vexp2(float x) {
    float r;
    asm volatile("v_exp_f32 %0, %1\n\ts_nop 1" : "=v"(r) : "v"(x));
    return r;
}
#endif

// ---------------- Kernel 1: CPB MLP -> btT[h][765] = 16*sigmoid(mlp)*log2(e) ----
__global__ __launch_bounds__(64) void cpb_kernel(const float* __restrict__ table,
                                                 const float* __restrict__ w1,
                                                 const float* __restrict__ b1,
                                                 const float* __restrict__ w2,
                                                 float* __restrict__ btT)
{
    int r = blockIdx.x;
    int l = threadIdx.x;
    float t0 = table[r * 2 + 0];
    float t1 = table[r * 2 + 1];
    float part[8];
#pragma unroll
    for (int h = 0; h < 8; ++h) part[h] = 0.f;
    for (int j = l; j < RPE_H; j += 64) {
        float hv = fmaf(t0, w1[j * 2 + 0], fmaf(t1, w1[j * 2 + 1], b1[j]));
        hv = fmaxf(hv, 0.f);
#pragma unroll
        for (int h = 0; h < 8; ++h)
            part[h] = fmaf(hv, w2[h * RPE_H + j], part[h]);
    }
#pragma unroll
    for (int h = 0; h < 8; ++h) {
#pragma unroll
        for (int off = 32; off > 0; off >>= 1)
            part[h] += __shfl_xor(part[h], off, 64);
    }
    if (l == 0) {
#pragma unroll
        for (int h = 0; h < 8; ++h)
            btT[h * TBL_R + r] = L2E * 16.f / (1.f + __expf(-part[h]));
    }
}

// ---------------- Kernel 2a: qkv GEMM per b, write Q->d_out, K/V^T->ws --------
// Q layout (inside d_out): per (b,h) at byte off ((b*80+h*10)*1024): [256 c][16 d] bf16,
// PRE-SCALED by log2(e). K: ws, per (b,h) 8192B: [256 e][16 d] bf16.
// V^T: ws, per (b,h) 8192B: [16 d][256 e], row d=10 = 1.0 (row-sum trick).
__global__ __launch_bounds__(512, 4) void qkv_kernel(const float* __restrict__ x,
                                                     const float* __restrict__ w_qkv,
                                                     const float* __restrict__ q_bias,
                                                     const float* __restrict__ v_bias,
                                                     char* __restrict__ qout,
                                                     char* __restrict__ kbufc,
                                                     char* __restrict__ vbufc)
{
    __shared__ __align__(16) char smem[53248];   // Xs[256][104] bf16, stride 208B
    const int tid = threadIdx.x, b = blockIdx.x;
    const int lane = tid & 63, w = tid >> 6;
    const int g = lane >> 4, m = lane & 15;

    bf16x8 zf;
#pragma unroll
    for (int i = 0; i < 8; ++i) zf[i] = (__bf16)0.0f;
    const f32x4 zacc = {0.f, 0.f, 0.f, 0.f};

    // stage Xs[c][n] bf16 (x transposed), zero-pad n=80..95
    {
        const float* xb = x + (size_t)b * (N_TOK * C_CH);
        for (int u = tid; u < 10240; u += 512) {
            int np = u >> 8, c = u & 255;
            float a0 = xb[(2 * np) * C_CH + c];
            float a1 = xb[(2 * np + 1) * C_CH + c];
            *(unsigned int*)(smem + c * 208 + np * 4) = bfb(a0) | (bfb(a1) << 16);
        }
        for (int u = tid; u < 2048; u += 512) {
            int c = u >> 3, np = u & 7;
            *(unsigned int*)(smem + c * 208 + 160 + np * 4) = 0u;
        }
    }
    __syncthreads();

    // each wave owns 3 of the 24 (s,h) tile-rows; all 16 c-tiles
#pragma unroll 1
    for (int i3 = 0; i3 < 3; ++i3) {
        const int sh = w * 3 + i3;          // 0..23
        const int s = sh >> 3, h = sh & 7;
        const float* wrow = w_qkv + (s * 80 + h * 10 + m) * 80;
        bf16x8 af[3];
#pragma unroll
        for (int ks = 0; ks < 3; ++ks) {
            bf16x8 f = zf;
            bool valid = (m < 10) && !(ks == 2 && g >= 2);
            if (valid) {
                const float* p = wrow + ks * 32 + g * 8;
                float4 l4 = *(const float4*)p;
                float4 h4 = *(const float4*)(p + 4);
                f[0] = (__bf16)l4.x; f[1] = (__bf16)l4.y; f[2] = (__bf16)l4.z; f[3] = (__bf16)l4.w;
                f[4] = (__bf16)h4.x; f[5] = (__bf16)h4.y; f[6] = (__bf16)h4.z; f[7] = (__bf16)h4.w;
            }
            af[ks] = f;
        }
        float bias_r[4];
#pragma unroll
        for (int r = 0; r < 4; ++r) {
            int dd = 4 * g + r;
            float bv = 0.f;
            if (dd < 10) {
                if (s == 0) bv = q_bias[h * 10 + dd];
                else if (s == 2) bv = v_bias[h * 10 + dd];
            }
            bias_r[r] = bv;
        }
        char* qb = qout + ((size_t)b * 80 + h * 10) * 1024;
        char* kb = kbufc + ((size_t)b * 8 + h) * 8192;
        char* vb = vbufc + ((size_t)b * 8 + h) * 8192;

#pragma unroll 2
        for (int ct = 0; ct < 16; ++ct) {
            f32x4 acc = zacc;
#pragma unroll
            for (int ks = 0; ks < 3; ++ks) {
                bf16x8 bfr = *(const bf16x8*)(smem + (16 * ct + m) * 208 + ks * 64 + g * 16);
                acc = __builtin_amdgcn_mfma_f32_16x16x32_bf16(af[ks], bfr, acc, 0, 0, 0);
            }
            int c = 16 * ct + m;
#pragma unroll
            for (int r = 0; r < 4; ++r) acc[r] += bias_r[r];
            if (s < 2) {
                float ss = acc[0]*acc[0] + acc[1]*acc[1] + acc[2]*acc[2] + acc[3]*acc[3];
                ss += __shfl_xor(ss, 16);
                ss += __shfl_xor(ss, 32);
                // Q gets log2(e) folded in so QK^T emerges pre-scaled for exp2
                float inv = ((s == 0) ? L2E : 1.f) / (sqrtf(ss) + EPS_);
                ull pk = (ull)bfb(acc[0] * inv) | ((ull)bfb(acc[1] * inv) << 16)
                       | ((ull)bfb(acc[2] * inv) << 32) | ((ull)bfb(acc[3] * inv) << 48);
                if (s == 0) *(ull*)(qb + c * 32 + g * 8) = pk;
                else        *(ull*)(kb + c * 32 + g * 8) = pk;
            } else {
#pragma unroll
                for (int r = 0; r < 4; ++r) {
                    int dd = 4 * g + r;
                    float vv = (dd == 10) ? 1.0f : acc[r];   // ones-row for row sums
                    *(__hip_bfloat16*)(vb + dd * 512 + c * 2) = __float2bfloat16(vv);
                }
            }
        }
    }
}

// ---------------- Kernel 2b: attention per (b,h): bias in MFMA C-operand ------
__global__ __launch_bounds__(256, 6) void attn2_kernel(const char* qin,          // aliases out2!
                                                       const char* __restrict__ kbufc,
                                                       const char* __restrict__ vbufc,
                                                       const float* __restrict__ btT,
                                                       unsigned int* out2)       // aliases qin!
{
    __shared__ __align__(16) char smem[26624];   // PT[768] float2 + Ps[4][64][40] bf16
    const int tid = threadIdx.x;
    const int b = blockIdx.x >> 3, h = blockIdx.x & 7;
    const int lane = tid & 63, w = tid >> 6;
    const int g = lane >> 4, m = lane & 15;
    const int rows0 = w * 64;

    // reversed bias table as overlapping pairs: PT[i] = (btr[i], btr[i+1]),
    // btr[i] = btT[h][764-i]. Index i is in FLOAT units (overlapping pairs).
    float2* PT = (float2*)smem;
    {
        const float* bth = btT + h * TBL_R;
        for (int i = tid; i < 768; i += 256) {
            float x0 = (i <= 764) ? bth[764 - i] : 0.f;
            float x1 = (i <= 763) ? bth[763 - i] : 0.f;
            PT[i] = make_float2(x0, x1);
        }
    }
    char* PsB = smem + 6144 + w * 5120;

    const char* qb = qin + ((size_t)b * 80 + h * 10) * 1024;
    const char* kb = kbufc + ((size_t)b * 8 + h) * 8192;
    const char* vb = vbufc + ((size_t)b * 8 + h) * 8192;

    bf16x8 zf;
#pragma unroll
    for (int i = 0; i < 8; ++i) zf[i] = (__bf16)0.0f;
    const f32x4 zacc = {0.f, 0.f, 0.f, 0.f};

    bf16x8 qf[4];
#pragma unroll
    for (int t = 0; t < 4; ++t) {
        bf16x8 f = zf;
        if (lane < 32) f = *(const bf16x8*)(qb + (rows0 + t * 16 + m) * 32 + g * 16);
        qf[t] = f;
    }
    __syncthreads();   // PT ready

    // pair-table bases; per (e0i,et): base + 48*e0i + 24*et, read PT[.] and PT[.+3]
    const int lane_cpart = 382 - 3 * (m >> 1) - (m & 1) + 6 * g;
    const float2* ptp[4];
#pragma unroll
    for (int t = 0; t < 4; ++t)
        ptp[t] = PT + (lane_cpart - 3 * ((rows0 + t * 16) >> 1));

    f32x4 Oacc[4];
#pragma unroll
    for (int t = 0; t < 4; ++t) Oacc[t] = zacc;

#pragma unroll
    for (int e0i = 0; e0i < 8; ++e0i) {
        const int e0 = e0i * 32;
        bf16x8 kf[2];
#pragma unroll
        for (int et = 0; et < 2; ++et) {
            bf16x8 f = zf;
            if (lane < 32) f = *(const bf16x8*)(kb + (e0 + et * 16 + m) * 32 + g * 16);
            kf[et] = f;
        }
        // S^T tiles with bias preloaded into the C-operand:
        // D = K·Q(*log2e) + bias  -> exp2 input directly
#pragma unroll
        for (int et = 0; et < 2; ++et) {
#pragma unroll
            for (int t = 0; t < 4; ++t) {
                const float2* bp2 = ptp[t] + 48 * e0i + 24 * et;   // FLOAT-unit offset
                float2 lo2 = bp2[0], hi2 = bp2[3];
                f32x4 biasC = {lo2.x, lo2.y, hi2.x, hi2.y};
                f32x4 st = __builtin_amdgcn_mfma_f32_16x16x32_bf16(kf[et], qf[t], biasC, 0, 0, 0);
                unsigned int w0 = cvtpk(vexp2(st[0]), vexp2(st[1]));
                unsigned int w1 = cvtpk(vexp2(st[2]), vexp2(st[3]));
                *(ull*)(PsB + (t * 16 + m) * 80 + et * 32 + g * 8) =
                    (ull)w0 | ((ull)w1 << 32);
            }
        }
        bf16x8 vf = *(const bf16x8*)(vb + m * 512 + e0 * 2 + g * 16);
#pragma unroll
        for (int t = 0; t < 4; ++t) {
            bf16x8 pf = *(const bf16x8*)(PsB + (t * 16 + m) * 80 + g * 16);
            Oacc[t] = __builtin_amdgcn_mfma_f32_16x16x32_bf16(pf, vf, Oacc[t], 0, 0, 0);
        }
    }

    // row sums live in output column d=10
    float rinv[4][4];
#pragma unroll
    for (int t = 0; t < 4; ++t)
#pragma unroll
        for (int r = 0; r < 4; ++r)
            rinv[t][r] = 1.f / __shfl(Oacc[t][r], (lane & 48) + 10, 64);

    if (m < 10) {
        unsigned int* op = out2 + ((size_t)b * 80 + h * 10 + m) * 256;
#pragma unroll
        for (int t = 0; t < 4; ++t) {
            unsigned int wd[4];
#pragma unroll
            for (int r = 0; r < 4; ++r) {
                float v = Oacc[t][r] * rinv[t][r];
                unsigned short hi = (unsigned short)bfb(v);
                float lo = v - bf2f(hi);
                wd[r] = (unsigned int)hi | (bfb(lo) << 16);
            }
            *(uint4*)(op + rows0 + t * 16 + 4 * g) = make_uint4(wd[0], wd[1], wd[2], wd[3]);
        }
    }
}

// ---------------- Fallback: fused mega (unchanged, self-consistent) -----------
#define XS_OFF 0
#define QH_OFF 53248
#define KH_OFF 69632
#define VT_OFF 94208
#define PS_OFF 111104
#define WL_OFF PS_OFF
#define BT_OFF 152064
#define SMEM_TOT 158208

__global__ __launch_bounds__(512, 2) void mega_kernel(const float* __restrict__ x,
                                                      const float* __restrict__ w_qkv,
                                                      const float* __restrict__ q_bias,
                                                      const float* __restrict__ v_bias,
                                                      const float* __restrict__ btT,
                                                      unsigned int* __restrict__ out2)
{
    __shared__ __align__(16) char smem[SMEM_TOT];
    const int tid = threadIdx.x;
    const int b = blockIdx.x;
    const int lane = tid & 63, w = tid >> 6;
    const int g = lane >> 4, m = lane & 15;

    bf16x8 zf;
#pragma unroll
    for (int i = 0; i < 8; ++i) zf[i] = (__bf16)0.0f;
    const f32x4 zacc = {0.f, 0.f, 0.f, 0.f};

    {
        const float* xb = x + (size_t)b * (N_TOK * C_CH);
        for (int u = tid; u < 10240; u += 512) {
            int np = u >> 8, c = u & 255;
            float a0 = xb[(2 * np) * C_CH + c];
            float a1 = xb[(2 * np + 1) * C_CH + c];
            *(unsigned int*)(smem + XS_OFF + c * 208 + np * 4) = bfb(a0) | (bfb(a1) << 16);
        }
        for (int u = tid; u < 2048; u += 512) {
            int c = u >> 3, np = u & 7;
            *(unsigned int*)(smem + XS_OFF + c * 208 + 160 + np * 4) = 0u;
        }
    }

    for (int hg = 0; hg < 4; ++hg) {
        __syncthreads();

        for (int u = tid; u < 96 * 52; u += 512) {
            int ri = u / 52, np = u - ri * 52;
            int m_ = ri & 15, sh = ri >> 4;
            unsigned int val = 0u;
            if (m_ < 10 && np < 40) {
                int s = sh >> 1, hl = sh & 1;
                const float* wr = w_qkv + ((s * 80) + (hg * 2 + hl) * 10 + m_) * 80 + 2 * np;
                val = bfb(wr[0]) | (bfb(wr[1]) << 16);
            }
            *(unsigned int*)(smem + WL_OFF + ri * 208 + np * 4) = val;
        }
        for (int i = tid; i < 2 * TBL_R; i += 512) {
            int hl = (i >= TBL_R) ? 1 : 0;
            int r = i - hl * TBL_R;
            *(float*)(smem + BT_OFF + (hl * 768 + r) * 4) =
                btT[(hg * 2 + hl) * TBL_R + (764 - r)];
        }
        __syncthreads();

        for (int sh = 0; sh < 6; ++sh) {
            int s = sh >> 1, hl = sh & 1, h = hg * 2 + hl;
            const char* wrow = smem + WL_OFF + (sh * 16 + m) * 208;
            bf16x8 af[3];
#pragma unroll
            for (int ks = 0; ks < 3; ++ks)
                af[ks] = *(const bf16x8*)(wrow + ks * 64 + g * 16);
            float bias_r[4];
#pragma unroll
            for (int r = 0; r < 4; ++r) {
                int dd = 4 * g + r;
                float bv = 0.f;
                if (dd < 10) {
                    if (s == 0) bv = q_bias[h * 10 + dd];
                    else if (s == 2) bv = v_bias[h * 10 + dd];
                }
                bias_r[r] = bv;
            }
#pragma unroll
            for (int ct2 = 0; ct2 < 2; ++ct2) {
                int ct = w + ct2 * 8;
                f32x4 acc = zacc;
#pragma unroll
                for (int ks = 0; ks < 3; ++ks) {
                    bf16x8 bfr = *(const bf16x8*)(smem + XS_OFF + (16 * ct + m) * 208 + ks * 64 + g * 16);
                    acc = __builtin_amdgcn_mfma_f32_16x16x32_bf16(af[ks], bfr, acc, 0, 0, 0);
                }
                int c = 16 * ct + m;
#pragma unroll
                for (int r = 0; r < 4; ++r) acc[r] += bias_r[r];
                if (s < 2) {
                    float ss = acc[0]*acc[0] + acc[1]*acc[1] + acc[2]*acc[2] + acc[3]*acc[3];
                    ss += __shfl_xor(ss, 16);
                    ss += __shfl_xor(ss, 32);
                    float inv = 1.f / (sqrtf(ss) + EPS_);
                    ull pk = (ull)bfb(acc[0] * inv) | ((ull)bfb(acc[1] * inv) << 16)
                           | ((ull)bfb(acc[2] * inv) << 32) | ((ull)bfb(acc[3] * inv) << 48);
                    if (s == 0) *(ull*)(smem + QH_OFF + (hl * 256 + c) * 32 + g * 8) = pk;
                    else        *(ull*)(smem + KH_OFF + (hl * 256 + c) * 48 + g * 8) = pk;
                } else {
#pragma unroll
                    for (int r = 0; r < 4; ++r) {
                        int dd = 4 * g + r;
                        float vv = acc[r];
                        if (r == 2) vv = (g == 2) ? 1.0f : vv;
                        *(__hip_bfloat16*)(smem + VT_OFF + (hl * 16 + dd) * 528 + c * 2) =
                            __float2bfloat16(vv);
                    }
                }
            }
        }
        __syncthreads();

        const int hl2 = w >> 2, h2 = hg * 2 + hl2;
        const int rows0 = (w & 3) * 64;
        const char* QhB = smem + QH_OFF + hl2 * (256 * 32);
        const char* KhB = smem + KH_OFF + hl2 * (256 * 48);
        const char* VtB = smem + VT_OFF + hl2 * (16 * 528);
        const float* btl = (const float*)(smem + BT_OFF) + hl2 * 768;
        char* PsB = smem + PS_OFF + w * 5120;

        bf16x8 qf[4];
#pragma unroll
        for (int t = 0; t < 4; ++t) {
            bf16x8 f = zf;
            if (lane < 32) f = *(const bf16x8*)(QhB + (rows0 + t * 16 + m) * 32 + g * 16);
            qf[t] = f;
        }
        const int lane_cpart = 382 - 3 * (m >> 1) - (m & 1) + 6 * g;
        const float* btp[4];
#pragma unroll
        for (int t = 0; t < 4; ++t)
            btp[t] = btl + (lane_cpart - 3 * ((rows0 + t * 16) >> 1));

        f32x4 Oacc[4];
#pragma unroll
        for (int t = 0; t < 4; ++t) Oacc[t] = zacc;

#pragma unroll
        for (int e0i = 0; e0i < 8; ++e0i) {
            const int e0 = e0i * 32;
            bf16x8 kf[2];
#pragma unroll
            for (int et = 0; et < 2; ++et) {
                bf16x8 f = zf;
                if (lane < 32) f = *(const bf16x8*)(KhB + (e0 + et * 16 + m) * 48 + g * 16);
                kf[et] = f;
            }
            f32x4 st[2][4];
#pragma unroll
            for (int et = 0; et < 2; ++et)
#pragma unroll
                for (int t = 0; t < 4; ++t)
                    st[et][t] = __builtin_amdgcn_mfma_f32_16x16x32_bf16(kf[et], qf[t], zacc, 0, 0, 0);
#pragma unroll
            for (int et = 0; et < 2; ++et) {
#pragma unroll
                for (int t = 0; t < 4; ++t) {
                    const float* bp = btp[t] + 48 * e0i + 24 * et;
                    float p0 = exp2f(fmaf(st[et][t][0], L2E, bp[0]));
                    float p1 = exp2f(fmaf(st[et][t][1], L2E, bp[1]));
                    float p2 = exp2f(fmaf(st[et][t][2], L2E, bp[3]));
                    float p3 = exp2f(fmaf(st[et][t][3], L2E, bp[4]));
                    unsigned int w0 = cvtpk(p0, p1);
                    unsigned int w1 = cvtpk(p2, p3);
                    *(ull*)(PsB + (t * 16 + m) * 80 + et * 32 + g * 8) =
                        (ull)w0 | ((ull)w1 << 32);
                }
            }
            bf16x8 vf = *(const bf16x8*)(VtB + m * 528 + e0 * 2 + g * 16);
#pragma unroll
            for (int t = 0; t < 4; ++t) {
                bf16x8 pf = *(const bf16x8*)(PsB + (t * 16 + m) * 80 + g * 16);
                Oacc[t] = __builtin_amdgcn_mfma_f32_16x16x32_bf16(pf, vf, Oacc[t], 0, 0, 0);
            }
        }

        float rinv[4][4];
#pragma unroll
        for (int t = 0; t < 4; ++t)
#pragma unroll
            for (int r = 0; r < 4; ++r)
                rinv[t][r] = 1.f / __shfl(Oacc[t][r], (lane & 48) + 10, 64);

        if (m < 10) {
            unsigned int* op = out2 + ((size_t)b * 80 + h2 * 10 + m) * 256;
#pragma unroll
            for (int t = 0; t < 4; ++t) {
                unsigned int wd[4];
#pragma unroll
                for (int r = 0; r < 4; ++r) {
                    float v = Oacc[t][r] * rinv[t][r];
                    unsigned short hi = (unsigned short)bfb(v);
                    float lo = v - bf2f(hi);
                    wd[r] = (unsigned int)hi | (bfb(lo) << 16);
                }
                *(uint4*)(op + rows0 + t * 16 + 4 * g) =
                    make_uint4(wd[0], wd[1], wd[2], wd[3]);
            }
        }
    }
}

// ---------------- Kernel 3: proj MFMA per (b, c-half), in-place safe ----------
__global__ __launch_bounds__(512, 2) void proj_kernel2(const unsigned int* __restrict__ out2,
                                                       const float* __restrict__ proj_w,
                                                       const float* __restrict__ proj_b,
                                                       float* __restrict__ out)
{
    __shared__ __align__(16) char smem[69888];  // Blds[128][336] + Wdup[80][336]
    const int tid = threadIdx.x;
    const int b = blockIdx.x >> 1, ch = blockIdx.x & 1;
    const int lane = tid & 63, w = tid >> 6;
    const int g = lane >> 4, m = lane & 15;

    const unsigned int* src = out2 + (size_t)b * (80 * 256) + ch * 128;
    for (int u = tid; u < 80 * 128; u += 512) {
        int n = u >> 7, cl = u & 127;
        *(unsigned int*)(smem + cl * 336 + n * 4) = src[n * 256 + cl];
    }
    for (int u = tid; u < 6400; u += 512) {
        int no = u / 80, n = u - no * 80;
        unsigned int wb = bfb(proj_w[u]);
        *(unsigned int*)(smem + 43008 + no * 336 + n * 4) = wb | (wb << 16);
    }
    __syncthreads();

    const f32x4 zacc = {0.f, 0.f, 0.f, 0.f};
    for (int tt = w; tt < 40; tt += 8) {
        int nt = tt >> 3, ct = tt & 7;
        f32x4 acc = zacc;
#pragma unroll
        for (int ks = 0; ks < 5; ++ks) {
            bf16x8 afr = *(const bf16x8*)(smem + 43008 + (nt * 16 + m) * 336 + ks * 64 + g * 16);
            bf16x8 bfr = *(const bf16x8*)(smem + (16 * ct + m) * 336 + ks * 64 + g * 16);
            acc = __builtin_amdgcn_mfma_f32_16x16x32_bf16(afr, bfr, acc, 0, 0, 0);
        }
        int cc = ch * 128 + 16 * ct + m;
        float* dst = out + (size_t)b * (80 * 256) + cc;
#pragma unroll
        for (int r = 0; r < 4; ++r) {
            int no = nt * 16 + 4 * g + r;
            dst[no * 256] = acc[r] + proj_b[no];
        }
    }
}

extern "C" void kernel_launch(void* const* d_in, const int* in_sizes, int n_in,
                              void* d_out, int out_size, void* d_ws, size_t ws_size,
                              hipStream_t stream) {
    const float* x        = (const float*)d_in[0];
    const float* w_qkv    = (const float*)d_in[1];
    const float* q_bias   = (const float*)d_in[2];
    const float* v_bias   = (const float*)d_in[3];
    const float* w1       = (const float*)d_in[4];
    const float* b1       = (const float*)d_in[5];
    const float* w2       = (const float*)d_in[6];
    const float* proj_w   = (const float*)d_in[7];
    const float* proj_b   = (const float*)d_in[8];
    const float* table    = (const float*)d_in[9];
    float* out = (float*)d_out;

    float* btT = (float*)d_ws;   // [8][765] f32 @ ws+0 (32KB slot)

    cpb_kernel<<<TBL_R, 64, 0, stream>>>(table, w1, b1, w2, btT);

    const size_t NEED = 32768ULL + 2ULL * 16777216ULL;  // btT + K(16MB) + V(16MB)
    if (ws_size >= NEED) {
        char* kbufc = (char*)d_ws + 32768;
        char* vbufc = kbufc + 16777216;
        qkv_kernel<<<B_SZ, 512, 0, stream>>>(x, w_qkv, q_bias, v_bias,
                                             (char*)d_out, kbufc, vbufc);
        attn2_kernel<<<B_SZ * 8, 256, 0, stream>>>((const char*)d_out, kbufc, vbufc,
                                                   btT, (unsigned int*)d_out);
    } else {
        mega_kernel<<<B_SZ, 512, 0, stream>>>(x, w_qkv, q_bias, v_bias, btT,
                                              (unsigned int*)d_out);
    }
    proj_kernel2<<<B_SZ * 2, 512, 0, stream>>>((const unsigned int*)d_out,
                                               proj_w, proj_b, out);
}

// Round 9
// 76.005 us; speedup vs baseline: 2.4777x; 1.1081x over previous
//
#include <hip/hip_runtime.h>
#include <hip/hip_bf16.h>

// GroupAttention: split-kernel MFMA pipeline. B=256, N=80, C=256, H=8, hd=10.
// qkv_kernel (per b; Q pre-scaled by log2e; cpb fused into extra blocks)
// -> attn2_kernel (per (b,h); float4 bias table read as one b128; bias via
// MFMA C-operand; hw exp2 softmax) -> proj_kernel2.
// Q lives inside d_out (slot each attn block later overwrites).
// Fallback to fused mega_kernel if ws_size < 32MB+32KB.

#define B_SZ   256
#define N_TOK  80
#define C_CH   256
#define RPE_H  512
#define TBL_R  765
#define EPS_   5e-5f
#define L2E    1.44269504088896f

typedef __bf16 bf16x8 __attribute__((ext_vector_type(8)));
typedef float  f32x4  __attribute__((ext_vector_type(4)));
typedef unsigned long long ull;

__device__ inline unsigned int bfb(float f) {
    __hip_bfloat16 h = __float2bfloat16(f);
    return (unsigned int)reinterpret_cast<unsigned short&>(h);
}
__device__ inline float bf2f(unsigned short u) {
    unsigned int w = ((unsigned int)u) << 16;
    return __uint_as_float(w);
}
__device__ inline unsigned int cvtpk(float lo, float hi) {
    unsigned int r;
    asm("v_cvt_pk_bf16_f32 %0, %1, %2" : "=v"(r) : "v"(lo), "v"(hi));
    return r;
}
// hardware exp2 via builtin (compiler handles TRANS->VALU hazard; R7 lesson)
#if defined(__has_builtin) && __has_builtin(__builtin_amdgcn_exp2f)
__device__ inline float vexp2(float x) { return __builtin_amdgcn_exp2f(x); }
#else
__device__ inline float vexp2(float x) {
    float r;
    asm volatile("v_exp_f32 %0, %1\n\ts_nop 1" : "=v"(r) : "v"(x));
    return r;
}
#endif

// ---------------- Kernel 1 (fallback path only): CPB MLP ------------------------
__global__ __launch_bounds__(64) void cpb_kernel(const float* __restrict__ table,
                                                 const float* __restrict__ w1,
                                                 const float* __restrict__ b1,
                                                 const float* __restrict__ w2,
                                                 float* __restrict__ btT)
{
    int r = blockIdx.x;
    int l = threadIdx.x;
    float t0 = table[r * 2 + 0];
    float t1 = table[r * 2 + 1];
    float part[8];
#pragma unroll
    for (int h = 0; h < 8; ++h) part[h] = 0.f;
    for (int j = l; j < RPE_H; j += 64) {
        float hv = fmaf(t0, w1[j * 2 + 0], fmaf(t1, w1[j * 2 + 1], b1[j]));
        hv = fmaxf(hv, 0.f);
#pragma unroll
        for (int h = 0; h < 8; ++h)
            part[h] = fmaf(hv, w2[h * RPE_H + j], part[h]);
    }
#pragma unroll
    for (int h = 0; h < 8; ++h) {
#pragma unroll
        for (int off = 32; off > 0; off >>= 1)
            part[h] += __shfl_xor(part[h], off, 64);
    }
    if (l == 0) {
#pragma unroll
        for (int h = 0; h < 8; ++h)
            btT[h * TBL_R + r] = L2E * 16.f / (1.f + __expf(-part[h]));
    }
}

// ---------------- Kernel 2a: qkv GEMM per b (+ fused CPB blocks) --------------
// blocks 0..255: qkv for batch b. blocks 256..351: CPB rows (8 rows/block, 1/wave).
// Q (inside d_out) per (b,h) at ((b*80+h*10)*1024): [256 c][16 d] bf16, *log2e.
// K: ws per (b,h) 8192B [256 e][16 d]. V^T: ws per (b,h) 8192B [16 d][256 e],
// row d=10 = 1.0 (MFMA row-sum trick).
__global__ __launch_bounds__(512, 4) void qkv_kernel(const float* __restrict__ x,
                                                     const float* __restrict__ w_qkv,
                                                     const float* __restrict__ q_bias,
                                                     const float* __restrict__ v_bias,
                                                     const float* __restrict__ table,
                                                     const float* __restrict__ w1,
                                                     const float* __restrict__ b1,
                                                     const float* __restrict__ w2,
                                                     char* __restrict__ qout,
                                                     char* __restrict__ kbufc,
                                                     char* __restrict__ vbufc,
                                                     float* __restrict__ btT)
{
    __shared__ __align__(16) char smem[53248];   // Xs[256][104] bf16, stride 208B
    const int tid = threadIdx.x;
    const int lane = tid & 63, w = tid >> 6;
    const int g = lane >> 4, m = lane & 15;

    // ---- fused CPB blocks ----
    if (blockIdx.x >= 256) {
        int r = (blockIdx.x - 256) * 8 + w;
        if (r < TBL_R) {
            int l = lane;
            float t0 = table[r * 2 + 0];
            float t1 = table[r * 2 + 1];
            float part[8];
#pragma unroll
            for (int h = 0; h < 8; ++h) part[h] = 0.f;
            for (int j = l; j < RPE_H; j += 64) {
                float hv = fmaf(t0, w1[j * 2 + 0], fmaf(t1, w1[j * 2 + 1], b1[j]));
                hv = fmaxf(hv, 0.f);
#pragma unroll
                for (int h = 0; h < 8; ++h)
                    part[h] = fmaf(hv, w2[h * RPE_H + j], part[h]);
            }
#pragma unroll
            for (int h = 0; h < 8; ++h) {
#pragma unroll
                for (int off = 32; off > 0; off >>= 1)
                    part[h] += __shfl_xor(part[h], off, 64);
            }
            if (l == 0) {
#pragma unroll
                for (int h = 0; h < 8; ++h)
                    btT[h * TBL_R + r] = L2E * 16.f / (1.f + __expf(-part[h]));
            }
        }
        return;
    }

    const int b = blockIdx.x;
    bf16x8 zf;
#pragma unroll
    for (int i = 0; i < 8; ++i) zf[i] = (__bf16)0.0f;
    const f32x4 zacc = {0.f, 0.f, 0.f, 0.f};

    // stage Xs[c][n] bf16 (x transposed), zero-pad n=80..95
    {
        const float* xb = x + (size_t)b * (N_TOK * C_CH);
        for (int u = tid; u < 10240; u += 512) {
            int np = u >> 8, c = u & 255;
            float a0 = xb[(2 * np) * C_CH + c];
            float a1 = xb[(2 * np + 1) * C_CH + c];
            *(unsigned int*)(smem + c * 208 + np * 4) = bfb(a0) | (bfb(a1) << 16);
        }
        for (int u = tid; u < 2048; u += 512) {
            int c = u >> 3, np = u & 7;
            *(unsigned int*)(smem + c * 208 + 160 + np * 4) = 0u;
        }
    }
    __syncthreads();

    // each wave owns 3 of the 24 (s,h) tile-rows; all 16 c-tiles
#pragma unroll 1
    for (int i3 = 0; i3 < 3; ++i3) {
        const int sh = w * 3 + i3;          // 0..23
        const int s = sh >> 3, h = sh & 7;
        const float* wrow = w_qkv + (s * 80 + h * 10 + m) * 80;
        bf16x8 af[3];
#pragma unroll
        for (int ks = 0; ks < 3; ++ks) {
            bf16x8 f = zf;
            bool valid = (m < 10) && !(ks == 2 && g >= 2);
            if (valid) {
                const float* p = wrow + ks * 32 + g * 8;
                float4 l4 = *(const float4*)p;
                float4 h4 = *(const float4*)(p + 4);
                f[0] = (__bf16)l4.x; f[1] = (__bf16)l4.y; f[2] = (__bf16)l4.z; f[3] = (__bf16)l4.w;
                f[4] = (__bf16)h4.x; f[5] = (__bf16)h4.y; f[6] = (__bf16)h4.z; f[7] = (__bf16)h4.w;
            }
            af[ks] = f;
        }
        float bias_r[4];
#pragma unroll
        for (int r = 0; r < 4; ++r) {
            int dd = 4 * g + r;
            float bv = 0.f;
            if (dd < 10) {
                if (s == 0) bv = q_bias[h * 10 + dd];
                else if (s == 2) bv = v_bias[h * 10 + dd];
            }
            bias_r[r] = bv;
        }
        char* qb = qout + ((size_t)b * 80 + h * 10) * 1024;
        char* kb = kbufc + ((size_t)b * 8 + h) * 8192;
        char* vb = vbufc + ((size_t)b * 8 + h) * 8192;

#pragma unroll 2
        for (int ct = 0; ct < 16; ++ct) {
            f32x4 acc = zacc;
#pragma unroll
            for (int ks = 0; ks < 3; ++ks) {
                bf16x8 bfr = *(const bf16x8*)(smem + (16 * ct + m) * 208 + ks * 64 + g * 16);
                acc = __builtin_amdgcn_mfma_f32_16x16x32_bf16(af[ks], bfr, acc, 0, 0, 0);
            }
            int c = 16 * ct + m;
#pragma unroll
            for (int r = 0; r < 4; ++r) acc[r] += bias_r[r];
            if (s < 2) {
                float ss = acc[0]*acc[0] + acc[1]*acc[1] + acc[2]*acc[2] + acc[3]*acc[3];
                ss += __shfl_xor(ss, 16);
                ss += __shfl_xor(ss, 32);
                // Q gets log2(e) folded in so QK^T emerges pre-scaled for exp2
                float inv = ((s == 0) ? L2E : 1.f) / (sqrtf(ss) + EPS_);
                ull pk = (ull)bfb(acc[0] * inv) | ((ull)bfb(acc[1] * inv) << 16)
                       | ((ull)bfb(acc[2] * inv) << 32) | ((ull)bfb(acc[3] * inv) << 48);
                if (s == 0) *(ull*)(qb + c * 32 + g * 8) = pk;
                else        *(ull*)(kb + c * 32 + g * 8) = pk;
            } else {
#pragma unroll
                for (int r = 0; r < 4; ++r) {
                    int dd = 4 * g + r;
                    float vv = (dd == 10) ? 1.0f : acc[r];   // ones-row for row sums
                    *(__hip_bfloat16*)(vb + dd * 512 + c * 2) = __float2bfloat16(vv);
                }
            }
        }
    }
}

// ---------------- Kernel 2b: attention per (b,h): float4 bias, C-operand ------
__global__ __launch_bounds__(256, 5) void attn2_kernel(const char* qin,          // aliases out2!
                                                       const char* __restrict__ kbufc,
                                                       const char* __restrict__ vbufc,
                                                       const float* __restrict__ btT,
                                                       unsigned int* out2)       // aliases qin!
{
    __shared__ __align__(16) char smem[32768];   // PT4[768] float4 (12KB) + Ps[4][64][40] bf16 (20KB)
    const int tid = threadIdx.x;
    const int b = blockIdx.x >> 3, h = blockIdx.x & 7;
    const int lane = tid & 63, w = tid >> 6;
    const int g = lane >> 4, m = lane & 15;
    const int rows0 = w * 64;

    // reversed bias table as float4: PT4[i] = (btr[i], btr[i+1], btr[i+3], btr[i+4]),
    // btr[i] = btT[h][764-i]. One ds_read_b128 delivers a whole C-operand bias.
    float4* PT4 = (float4*)smem;
    {
        const float* bth = btT + h * TBL_R;
        for (int i = tid; i < 768; i += 256) {
            float x0 = (i <= 764) ? bth[764 - i] : 0.f;
            float x1 = (i <= 763) ? bth[763 - i] : 0.f;
            float x2 = (i <= 761) ? bth[761 - i] : 0.f;
            float x3 = (i <= 760) ? bth[760 - i] : 0.f;
            PT4[i] = make_float4(x0, x1, x2, x3);
        }
    }
    char* PsB = smem + 12288 + w * 5120;

    const char* qb = qin + ((size_t)b * 80 + h * 10) * 1024;
    const char* kb = kbufc + ((size_t)b * 8 + h) * 8192;
    const char* vb = vbufc + ((size_t)b * 8 + h) * 8192;

    bf16x8 zf;
#pragma unroll
    for (int i = 0; i < 8; ++i) zf[i] = (__bf16)0.0f;
    const f32x4 zacc = {0.f, 0.f, 0.f, 0.f};

    bf16x8 qf[4];
#pragma unroll
    for (int t = 0; t < 4; ++t) {
        bf16x8 f = zf;
        if (lane < 32) f = *(const bf16x8*)(qb + (rows0 + t * 16 + m) * 32 + g * 16);
        qf[t] = f;
    }
    __syncthreads();   // PT4 ready

    // table bases; per (e0i,et): one b128 at base + 48*e0i + 24*et
    const int lane_cpart = 382 - 3 * (m >> 1) - (m & 1) + 6 * g;
    const float4* ptp[4];
#pragma unroll
    for (int t = 0; t < 4; ++t)
        ptp[t] = PT4 + (lane_cpart - 3 * ((rows0 + t * 16) >> 1));

    f32x4 Oacc[4];
#pragma unroll
    for (int t = 0; t < 4; ++t) Oacc[t] = zacc;

#pragma unroll
    for (int e0i = 0; e0i < 8; ++e0i) {
        const int e0 = e0i * 32;
        bf16x8 kf[2];
#pragma unroll
        for (int et = 0; et < 2; ++et) {
            bf16x8 f = zf;
            if (lane < 32) f = *(const bf16x8*)(kb + (e0 + et * 16 + m) * 32 + g * 16);
            kf[et] = f;
        }
        // S^T tiles with bias preloaded into the C-operand:
        // D = K·Q(*log2e) + bias  -> exp2 input directly
#pragma unroll
        for (int et = 0; et < 2; ++et) {
#pragma unroll
            for (int t = 0; t < 4; ++t) {
                float4 bq = ptp[t][48 * e0i + 24 * et];
                f32x4 biasC = {bq.x, bq.y, bq.z, bq.w};
                f32x4 st = __builtin_amdgcn_mfma_f32_16x16x32_bf16(kf[et], qf[t], biasC, 0, 0, 0);
                unsigned int w0 = cvtpk(vexp2(st[0]), vexp2(st[1]));
                unsigned int w1 = cvtpk(vexp2(st[2]), vexp2(st[3]));
                *(ull*)(PsB + (t * 16 + m) * 80 + et * 32 + g * 8) =
                    (ull)w0 | ((ull)w1 << 32);
            }
        }
        bf16x8 vf = *(const bf16x8*)(vb + m * 512 + e0 * 2 + g * 16);
#pragma unroll
        for (int t = 0; t < 4; ++t) {
            bf16x8 pf = *(const bf16x8*)(PsB + (t * 16 + m) * 80 + g * 16);
            Oacc[t] = __builtin_amdgcn_mfma_f32_16x16x32_bf16(pf, vf, Oacc[t], 0, 0, 0);
        }
    }

    // row sums live in output column d=10
    float rinv[4][4];
#pragma unroll
    for (int t = 0; t < 4; ++t)
#pragma unroll
        for (int r = 0; r < 4; ++r)
            rinv[t][r] = 1.f / __shfl(Oacc[t][r], (lane & 48) + 10, 64);

    if (m < 10) {
        unsigned int* op = out2 + ((size_t)b * 80 + h * 10 + m) * 256;
#pragma unroll
        for (int t = 0; t < 4; ++t) {
            unsigned int wd[4];
#pragma unroll
            for (int r = 0; r < 4; ++r) {
                float v = Oacc[t][r] * rinv[t][r];
                unsigned short hi = (unsigned short)bfb(v);
                float lo = v - bf2f(hi);
                wd[r] = (unsigned int)hi | (bfb(lo) << 16);
            }
            *(uint4*)(op + rows0 + t * 16 + 4 * g) = make_uint4(wd[0], wd[1], wd[2], wd[3]);
        }
    }
}

// ---------------- Fallback: fused mega (unchanged, self-consistent) -----------
#define XS_OFF 0
#define QH_OFF 53248
#define KH_OFF 69632
#define VT_OFF 94208
#define PS_OFF 111104
#define WL_OFF PS_OFF
#define BT_OFF 152064
#define SMEM_TOT 158208

__global__ __launch_bounds__(512, 2) void mega_kernel(const float* __restrict__ x,
                                                      const float* __restrict__ w_qkv,
                                                      const float* __restrict__ q_bias,
                                                      const float* __restrict__ v_bias,
                                                      const float* __restrict__ btT,
                                                      unsigned int* __restrict__ out2)
{
    __shared__ __align__(16) char smem[SMEM_TOT];
    const int tid = threadIdx.x;
    const int b = blockIdx.x;
    const int lane = tid & 63, w = tid >> 6;
    const int g = lane >> 4, m = lane & 15;

    bf16x8 zf;
#pragma unroll
    for (int i = 0; i < 8; ++i) zf[i] = (__bf16)0.0f;
    const f32x4 zacc = {0.f, 0.f, 0.f, 0.f};

    {
        const float* xb = x + (size_t)b * (N_TOK * C_CH);
        for (int u = tid; u < 10240; u += 512) {
            int np = u >> 8, c = u & 255;
            float a0 = xb[(2 * np) * C_CH + c];
            float a1 = xb[(2 * np + 1) * C_CH + c];
            *(unsigned int*)(smem + XS_OFF + c * 208 + np * 4) = bfb(a0) | (bfb(a1) << 16);
        }
        for (int u = tid; u < 2048; u += 512) {
            int c = u >> 3, np = u & 7;
            *(unsigned int*)(smem + XS_OFF + c * 208 + 160 + np * 4) = 0u;
        }
    }

    for (int hg = 0; hg < 4; ++hg) {
        __syncthreads();

        for (int u = tid; u < 96 * 52; u += 512) {
            int ri = u / 52, np = u - ri * 52;
            int m_ = ri & 15, sh = ri >> 4;
            unsigned int val = 0u;
            if (m_ < 10 && np < 40) {
                int s = sh >> 1, hl = sh & 1;
                const float* wr = w_qkv + ((s * 80) + (hg * 2 + hl) * 10 + m_) * 80 + 2 * np;
                val = bfb(wr[0]) | (bfb(wr[1]) << 16);
            }
            *(unsigned int*)(smem + WL_OFF + ri * 208 + np * 4) = val;
        }
        for (int i = tid; i < 2 * TBL_R; i += 512) {
            int hl = (i >= TBL_R) ? 1 : 0;
            int r = i - hl * TBL_R;
            *(float*)(smem + BT_OFF + (hl * 768 + r) * 4) =
                btT[(hg * 2 + hl) * TBL_R + (764 - r)];
        }
        __syncthreads();

        for (int sh = 0; sh < 6; ++sh) {
            int s = sh >> 1, hl = sh & 1, h = hg * 2 + hl;
            const char* wrow = smem + WL_OFF + (sh * 16 + m) * 208;
            bf16x8 af[3];
#pragma unroll
            for (int ks = 0; ks < 3; ++ks)
                af[ks] = *(const bf16x8*)(wrow + ks * 64 + g * 16);
            float bias_r[4];
#pragma unroll
            for (int r = 0; r < 4; ++r) {
                int dd = 4 * g + r;
                float bv = 0.f;
                if (dd < 10) {
                    if (s == 0) bv = q_bias[h * 10 + dd];
                    else if (s == 2) bv = v_bias[h * 10 + dd];
                }
                bias_r[r] = bv;
            }
#pragma unroll
            for (int ct2 = 0; ct2 < 2; ++ct2) {
                int ct = w + ct2 * 8;
                f32x4 acc = zacc;
#pragma unroll
                for (int ks = 0; ks < 3; ++ks) {
                    bf16x8 bfr = *(const bf16x8*)(smem + XS_OFF + (16 * ct + m) * 208 + ks * 64 + g * 16);
                    acc = __builtin_amdgcn_mfma_f32_16x16x32_bf16(af[ks], bfr, acc, 0, 0, 0);
                }
                int c = 16 * ct + m;
#pragma unroll
                for (int r = 0; r < 4; ++r) acc[r] += bias_r[r];
                if (s < 2) {
                    float ss = acc[0]*acc[0] + acc[1]*acc[1] + acc[2]*acc[2] + acc[3]*acc[3];
                    ss += __shfl_xor(ss, 16);
                    ss += __shfl_xor(ss, 32);
                    float inv = 1.f / (sqrtf(ss) + EPS_);
                    ull pk = (ull)bfb(acc[0] * inv) | ((ull)bfb(acc[1] * inv) << 16)
                           | ((ull)bfb(acc[2] * inv) << 32) | ((ull)bfb(acc[3] * inv) << 48);
                    if (s == 0) *(ull*)(smem + QH_OFF + (hl * 256 + c) * 32 + g * 8) = pk;
                    else        *(ull*)(smem + KH_OFF + (hl * 256 + c) * 48 + g * 8) = pk;
                } else {
#pragma unroll
                    for (int r = 0; r < 4; ++r) {
                        int dd = 4 * g + r;
                        float vv = acc[r];
                        if (r == 2) vv = (g == 2) ? 1.0f : vv;
                        *(__hip_bfloat16*)(smem + VT_OFF + (hl * 16 + dd) * 528 + c * 2) =
                            __float2bfloat16(vv);
                    }
                }
            }
        }
        __syncthreads();

        const int hl2 = w >> 2, h2 = hg * 2 + hl2;
        const int rows0 = (w & 3) * 64;
        const char* QhB = smem + QH_OFF + hl2 * (256 * 32);
        const char* KhB = smem + KH_OFF + hl2 * (256 * 48);
        const char* VtB = smem + VT_OFF + hl2 * (16 * 528);
        const float* btl = (const float*)(smem + BT_OFF) + hl2 * 768;
        char* PsB = smem + PS_OFF + w * 5120;

        bf16x8 qf[4];
#pragma unroll
        for (int t = 0; t < 4; ++t) {
            bf16x8 f = zf;
            if (lane < 32) f = *(const bf16x8*)(QhB + (rows0 + t * 16 + m) * 32 + g * 16);
            qf[t] = f;
        }
        const int lane_cpart = 382 - 3 * (m >> 1) - (m & 1) + 6 * g;
        const float* btp[4];
#pragma unroll
        for (int t = 0; t < 4; ++t)
            btp[t] = btl + (lane_cpart - 3 * ((rows0 + t * 16) >> 1));

        f32x4 Oacc[4];
#pragma unroll
        for (int t = 0; t < 4; ++t) Oacc[t] = zacc;

#pragma unroll
        for (int e0i = 0; e0i < 8; ++e0i) {
            const int e0 = e0i * 32;
            bf16x8 kf[2];
#pragma unroll
            for (int et = 0; et < 2; ++et) {
                bf16x8 f = zf;
                if (lane < 32) f = *(const bf16x8*)(KhB + (e0 + et * 16 + m) * 48 + g * 16);
                kf[et] = f;
            }
            f32x4 st[2][4];
#pragma unroll
            for (int et = 0; et < 2; ++et)
#pragma unroll
                for (int t = 0; t < 4; ++t)
                    st[et][t] = __builtin_amdgcn_mfma_f32_16x16x32_bf16(kf[et], qf[t], zacc, 0, 0, 0);
#pragma unroll
            for (int et = 0; et < 2; ++et) {
#pragma unroll
                for (int t = 0; t < 4; ++t) {
                    const float* bp = btp[t] + 48 * e0i + 24 * et;
                    float p0 = exp2f(fmaf(st[et][t][0], L2E, bp[0]));
                    float p1 = exp2f(fmaf(st[et][t][1], L2E, bp[1]));
                    float p2 = exp2f(fmaf(st[et][t][2], L2E, bp[3]));
                    float p3 = exp2f(fmaf(st[et][t][3], L2E, bp[4]));
                    unsigned int w0 = cvtpk(p0, p1);
                    unsigned int w1 = cvtpk(p2, p3);
                    *(ull*)(PsB + (t * 16 + m) * 80 + et * 32 + g * 8) =
                        (ull)w0 | ((ull)w1 << 32);
                }
            }
            bf16x8 vf = *(const bf16x8*)(VtB + m * 528 + e0 * 2 + g * 16);
#pragma unroll
            for (int t = 0; t < 4; ++t) {
                bf16x8 pf = *(const bf16x8*)(PsB + (t * 16 + m) * 80 + g * 16);
                Oacc[t] = __builtin_amdgcn_mfma_f32_16x16x32_bf16(pf, vf, Oacc[t], 0, 0, 0);
            }
        }

        float rinv[4][4];
#pragma unroll
        for (int t = 0; t < 4; ++t)
#pragma unroll
            for (int r = 0; r < 4; ++r)
                rinv[t][r] = 1.f / __shfl(Oacc[t][r], (lane & 48) + 10, 64);

        if (m < 10) {
            unsigned int* op = out2 + ((size_t)b * 80 + h2 * 10 + m) * 256;
#pragma unroll
            for (int t = 0; t < 4; ++t) {
                unsigned int wd[4];
#pragma unroll
                for (int r = 0; r < 4; ++r) {
                    float v = Oacc[t][r] * rinv[t][r];
                    unsigned short hi = (unsigned short)bfb(v);
                    float lo = v - bf2f(hi);
                    wd[r] = (unsigned int)hi | (bfb(lo) << 16);
                }
                *(uint4*)(op + rows0 + t * 16 + 4 * g) =
                    make_uint4(wd[0], wd[1], wd[2], wd[3]);
            }
        }
    }
}

// ---------------- Kernel 3: proj MFMA per (b, c-half), in-place safe ----------
__global__ __launch_bounds__(512, 2) void proj_kernel2(const unsigned int* __restrict__ out2,
                                                       const float* __restrict__ proj_w,
                                                       const float* __restrict__ proj_b,
                                                       float* __restrict__ out)
{
    __shared__ __align__(16) char smem[69888];  // Blds[128][336] + Wdup[80][336]
    const int tid = threadIdx.x;
    const int b = blockIdx.x >> 1, ch = blockIdx.x & 1;
    const int lane = tid & 63, w = tid >> 6;
    const int g = lane >> 4, m = lane & 15;

    const unsigned int* src = out2 + (size_t)b * (80 * 256) + ch * 128;
    for (int u = tid; u < 80 * 128; u += 512) {
        int n = u >> 7, cl = u & 127;
        *(unsigned int*)(smem + cl * 336 + n * 4) = src[n * 256 + cl];
    }
    for (int u = tid; u < 6400; u += 512) {
        int no = u / 80, n = u - no * 80;
        unsigned int wb = bfb(proj_w[u]);
        *(unsigned int*)(smem + 43008 + no * 336 + n * 4) = wb | (wb << 16);
    }
    __syncthreads();

    const f32x4 zacc = {0.f, 0.f, 0.f, 0.f};
    for (int tt = w; tt < 40; tt += 8) {
        int nt = tt >> 3, ct = tt & 7;
        f32x4 acc = zacc;
#pragma unroll
        for (int ks = 0; ks < 5; ++ks) {
            bf16x8 afr = *(const bf16x8*)(smem + 43008 + (nt * 16 + m) * 336 + ks * 64 + g * 16);
            bf16x8 bfr = *(const bf16x8*)(smem + (16 * ct + m) * 336 + ks * 64 + g * 16);
            acc = __builtin_amdgcn_mfma_f32_16x16x32_bf16(afr, bfr, acc, 0, 0, 0);
        }
        int cc = ch * 128 + 16 * ct + m;
        float* dst = out + (size_t)b * (80 * 256) + cc;
#pragma unroll
        for (int r = 0; r < 4; ++r) {
            int no = nt * 16 + 4 * g + r;
            dst[no * 256] = acc[r] + proj_b[no];
        }
    }
}

extern "C" void kernel_launch(void* const* d_in, const int* in_sizes, int n_in,
                              void* d_out, int out_size, void* d_ws, size_t ws_size,
                              hipStream_t stream) {
    const float* x        = (const float*)d_in[0];
    const float* w_qkv    = (const float*)d_in[1];
    const float* q_bias   = (const float*)d_in[2];
    const float* v_bias   = (const float*)d_in[3];
    const float* w1       = (const float*)d_in[4];
    const float* b1       = (const float*)d_in[5];
    const float* w2       = (const float*)d_in[6];
    const float* proj_w   = (const float*)d_in[7];
    const float* proj_b   = (const float*)d_in[8];
    const float* table    = (const float*)d_in[9];
    float* out = (float*)d_out;

    float* btT = (float*)d_ws;   // [8][765] f32 @ ws+0 (32KB slot)

    const size_t NEED = 32768ULL + 2ULL * 16777216ULL;  // btT + K(16MB) + V(16MB)
    if (ws_size >= NEED) {
        char* kbufc = (char*)d_ws + 32768;
        char* vbufc = kbufc + 16777216;
        // qkv blocks 0..255 + fused CPB blocks 256..351 (btT ready before attn2)
        qkv_kernel<<<B_SZ + 96, 512, 0, stream>>>(x, w_qkv, q_bias, v_bias,
                                                  table, w1, b1, w2,
                                                  (char*)d_out, kbufc, vbufc, btT);
        attn2_kernel<<<B_SZ * 8, 256, 0, stream>>>((const char*)d_out, kbufc, vbufc,
                                                   btT, (unsigned int*)d_out);
    } else {
        cpb_kernel<<<TBL_R, 64, 0, stream>>>(table, w1, b1, w2, btT);
        mega_kernel<<<B_SZ, 512, 0, stream>>>(x, w_qkv, q_bias, v_bias, btT,
                                              (unsigned int*)d_out);
    }
    proj_kernel2<<<B_SZ * 2, 512, 0, stream>>>((const unsigned int*)d_out,
                                               proj_w, proj_b, out);
}